// Round 7
// baseline (1070.259 us; speedup 1.0000x reference)
//
#include <hip/hip_runtime.h>
#include <hip/hip_bf16.h>

#define NN_NODES 100000
#define NE_EDGES 1000000
#define D_IN 512
#define D_H0 512
#define D_H1 256
#define D_C  64

using f32x4  = __attribute__((ext_vector_type(4))) float;
using h16x8  = __attribute__((ext_vector_type(8))) _Float16;

// ---------------- fp32 -> fp16, 8 elems/thread ----------------
__global__ __launch_bounds__(256) void tof16_kernel(
    const float* __restrict__ w, _Float16* __restrict__ o, int n8)
{
    int i = blockIdx.x * 256 + threadIdx.x;
    if (i >= n8) return;
    const f32x4 a = *(const f32x4*)(w + (size_t)i * 8);
    const f32x4 b = *(const f32x4*)(w + (size_t)i * 8 + 4);
    h16x8 h;
    #pragma unroll
    for (int j = 0; j < 4; j++){
        h[j]   = (_Float16)a[j];
        h[j+4] = (_Float16)b[j];
    }
    *(h16x8*)(o + (size_t)i * 8) = h;
}

// ---------------- GEMM: C[M,NNc] = act( A[M,K] * B[NNc,K]^T + bias ) ----------------
// Fully asynchronous register GEMM: NO LDS, NO barriers. Each wave owns a
// 64x64 output tile; A/B fragments are loaded global->VGPR (per-lane strided,
// same line pattern as LDS staging would use; B is L2-resident), register
// double-buffered with distance-1 prefetch. K fully unrolled: all loads use
// immediate offsets. Compiler inserts counted vmcnt from SSA deps; waves
// self-pace and cover each other's latency (3 waves/SIMD).
// WN = waves along N (2 -> block 128x128; 1 -> block 256x64).
// OMODE: 1 fp16 out; 2 dual out (O1=v fp32, O2=(v*scale[row]) fp16).
template<bool RELU, int OMODE, int WN, int NBN, int KK>
__global__ __launch_bounds__(256) void gemm_kernel(
    const _Float16* __restrict__ A,
    const _Float16* __restrict__ B,
    const float* __restrict__ bias,
    void* __restrict__ O1, _Float16* __restrict__ O2,
    const float* __restrict__ scale,
    int M, int NNc, int xq, int xr)
{
    constexpr int WMN = 4 / WN;          // waves along M
    constexpr int BMT = WMN * 64;        // block M tile
    constexpr int NT  = KK / 32;         // K steps

    const int tid  = threadIdx.x;
    const int lane = tid & 63;
    const int wv   = tid >> 6;
    const int wm   = wv / WN;
    const int wn   = wv % WN;
    const int fr   = lane & 15;
    const int fc   = lane >> 4;

    // bijective XCD-chunk swizzle (m204): bn varies fastest within an XCD
    const int bid = blockIdx.x;
    const int xcd = bid & 7;
    const int i8  = bid >> 3;
    const int L   = ((xcd < xr) ? xcd * (xq + 1) : xr * (xq + 1) + (xcd - xr) * xq) + i8;
    const int mt  = L / NBN;
    const int bn  = L - mt * NBN;
    const int bm0 = mt * BMT;
    const int bn0 = bn * (WN * 64);

    const _Float16* Ap[4];
    const _Float16* Bp[4];
    #pragma unroll
    for (int mf = 0; mf < 4; mf++){
        int r = bm0 + wm * 64 + mf * 16 + fr;
        if (r > M - 1) r = M - 1;            // tail tile: duplicate last row
        Ap[mf] = A + (size_t)r * KK + fc * 8;
    }
    #pragma unroll
    for (int nf = 0; nf < 4; nf++){
        int r = bn0 + wn * 64 + nf * 16 + fr;
        Bp[nf] = B + (size_t)r * KK + fc * 8;
    }

    f32x4 acc[4][4] = {};
    h16x8 a0[4], b0[4], a1[4], b1[4];

    // prologue: tile 0 into set0
    #pragma unroll
    for (int x = 0; x < 4; x++){
        a0[x] = *(const h16x8*)(Ap[x]);
        b0[x] = *(const h16x8*)(Bp[x]);
    }

    #pragma unroll
    for (int t = 0; t < NT - 2; t += 2){
        // prefetch tile t+1 -> set1, compute tile t (set0)
        #pragma unroll
        for (int x = 0; x < 4; x++){
            a1[x] = *(const h16x8*)(Ap[x] + (t + 1) * 32);
            b1[x] = *(const h16x8*)(Bp[x] + (t + 1) * 32);
        }
        __builtin_amdgcn_s_setprio(1);
        #pragma unroll
        for (int mf = 0; mf < 4; mf++)
            #pragma unroll
            for (int nf = 0; nf < 4; nf++)
                acc[mf][nf] = __builtin_amdgcn_mfma_f32_16x16x32_f16(a0[mf], b0[nf], acc[mf][nf], 0, 0, 0);
        __builtin_amdgcn_s_setprio(0);
        // prefetch tile t+2 -> set0, compute tile t+1 (set1)
        #pragma unroll
        for (int x = 0; x < 4; x++){
            a0[x] = *(const h16x8*)(Ap[x] + (t + 2) * 32);
            b0[x] = *(const h16x8*)(Bp[x] + (t + 2) * 32);
        }
        __builtin_amdgcn_s_setprio(1);
        #pragma unroll
        for (int mf = 0; mf < 4; mf++)
            #pragma unroll
            for (int nf = 0; nf < 4; nf++)
                acc[mf][nf] = __builtin_amdgcn_mfma_f32_16x16x32_f16(a1[mf], b1[nf], acc[mf][nf], 0, 0, 0);
        __builtin_amdgcn_s_setprio(0);
    }
    // peel: tile NT-2 is in set0; prefetch NT-1 -> set1
    #pragma unroll
    for (int x = 0; x < 4; x++){
        a1[x] = *(const h16x8*)(Ap[x] + (NT - 1) * 32);
        b1[x] = *(const h16x8*)(Bp[x] + (NT - 1) * 32);
    }
    __builtin_amdgcn_s_setprio(1);
    #pragma unroll
    for (int mf = 0; mf < 4; mf++)
        #pragma unroll
        for (int nf = 0; nf < 4; nf++)
            acc[mf][nf] = __builtin_amdgcn_mfma_f32_16x16x32_f16(a0[mf], b0[nf], acc[mf][nf], 0, 0, 0);
    #pragma unroll
    for (int mf = 0; mf < 4; mf++)
        #pragma unroll
        for (int nf = 0; nf < 4; nf++)
            acc[mf][nf] = __builtin_amdgcn_mfma_f32_16x16x32_f16(a1[mf], b1[nf], acc[mf][nf], 0, 0, 0);
    __builtin_amdgcn_s_setprio(0);

    // ---- epilogue ----
    #pragma unroll
    for (int mf = 0; mf < 4; mf++){
        #pragma unroll
        for (int nf = 0; nf < 4; nf++){
            #pragma unroll
            for (int r = 0; r < 4; r++){
                int rg = bm0 + wm * 64 + mf * 16 + fc * 4 + r;
                int cg = bn0 + wn * 64 + nf * 16 + fr;
                if (rg < M){
                    float v = acc[mf][nf][r] + bias[cg];
                    if constexpr (RELU) v = fmaxf(v, 0.f);
                    if constexpr (OMODE == 1)
                        ((_Float16*)O1)[(size_t)rg * NNc + cg] = (_Float16)v;
                    else {
                        ((float*)O1)[(size_t)rg * NNc + cg] = v;
                        O2[(size_t)rg * NNc + cg] = (_Float16)(v * scale[rg]);
                    }
                }
            }
        }
    }
}

// ---------------- graph preprocessing ----------------
__global__ void degrees_kernel(const int* __restrict__ src, const int* __restrict__ dst,
                               int* __restrict__ dout, int* __restrict__ din){
    int e = blockIdx.x * blockDim.x + threadIdx.x;
    if (e < NE_EDGES){
        atomicAdd(&dout[src[e]], 1);
        atomicAdd(&din[dst[e]], 1);
    }
}

__global__ void norm_kernel(const int* __restrict__ dout, const int* __restrict__ din,
                            float* __restrict__ ns, float* __restrict__ nd, int n){
    int i = blockIdx.x * blockDim.x + threadIdx.x;
    if (i < n){
        ns[i] = rsqrtf((float)(dout[i] > 1 ? dout[i] : 1));
        nd[i] = rsqrtf((float)(din[i]  > 1 ? din[i]  : 1));
    }
}

__global__ __launch_bounds__(256) void scan1_kernel(const int* __restrict__ din,
                                                    int* __restrict__ part,
                                                    int* __restrict__ bsum, int n){
    __shared__ int s[256];
    int i = blockIdx.x * 256 + threadIdx.x;
    int v = (i < n) ? din[i] : 0;
    s[threadIdx.x] = v;
    __syncthreads();
    for (int off = 1; off < 256; off <<= 1){
        int t = (threadIdx.x >= off) ? s[threadIdx.x - off] : 0;
        __syncthreads();
        s[threadIdx.x] += t;
        __syncthreads();
    }
    if (i < n) part[i] = s[threadIdx.x];
    if (threadIdx.x == 255) bsum[blockIdx.x] = s[255];
}

__global__ __launch_bounds__(512) void scan2_kernel(int* __restrict__ bsum, int nb){
    __shared__ int s[512];
    int v = (threadIdx.x < nb) ? bsum[threadIdx.x] : 0;
    s[threadIdx.x] = v;
    __syncthreads();
    for (int off = 1; off < 512; off <<= 1){
        int t = (threadIdx.x >= off) ? s[threadIdx.x - off] : 0;
        __syncthreads();
        s[threadIdx.x] += t;
        __syncthreads();
    }
    if (threadIdx.x < nb) bsum[threadIdx.x] = s[threadIdx.x];
}

__global__ void scan3_kernel(const int* __restrict__ part, const int* __restrict__ din,
                             const int* __restrict__ bsum, int* __restrict__ offs,
                             int* __restrict__ cur, int n){
    int i = blockIdx.x * 256 + threadIdx.x;
    if (i < n){
        int base = (blockIdx.x > 0) ? bsum[blockIdx.x - 1] : 0;
        int excl = base + part[i] - din[i];
        offs[i] = excl;
        cur[i]  = excl;
    }
}

__global__ void fill_kernel(const int* __restrict__ src, const int* __restrict__ dst,
                            int* __restrict__ cur, int* __restrict__ csr){
    int e = blockIdx.x * blockDim.x + threadIdx.x;
    if (e < NE_EDGES){
        int d = dst[e];
        int pos = atomicAdd(&cur[d], 1);
        csr[pos] = src[e];
    }
}

// ---------------- APPNP propagation (fp16 gather state) ----------------
__global__ __launch_bounds__(256) void propagate_kernel(
    const _Float16* __restrict__ hs, const float* __restrict__ h0,
    float* __restrict__ hout, _Float16* __restrict__ houts,
    const int* __restrict__ offs, const int* __restrict__ din,
    const int* __restrict__ csr,
    const float* __restrict__ ns, const float* __restrict__ nd)
{
    int wv   = threadIdx.x >> 6;
    int lane = threadIdx.x & 63;
    int grp  = lane >> 3;     // 0..7
    int gl   = lane & 7;      // 0..7
    int node = blockIdx.x * 4 + wv;
    if (node >= NN_NODES) return;
    int start = offs[node];
    int deg   = din[node];
    float acc[8] = {};
    for (int j = grp; j < deg; j += 8){
        int s = csr[start + j];
        h16x8 v = *(const h16x8*)(hs + (size_t)s * D_C + gl * 8);
        #pragma unroll
        for (int i = 0; i < 8; i++) acc[i] += (float)v[i];
    }
    #pragma unroll
    for (int i = 0; i < 8; i++){
        acc[i] += __shfl_xor(acc[i], 8, 64);
        acc[i] += __shfl_xor(acc[i], 16, 64);
        acc[i] += __shfl_xor(acc[i], 32, 64);
    }
    if (grp == 0){
        float ndv = nd[node];
        f32x4 h0a = *(const f32x4*)(h0 + (size_t)node * D_C + gl * 8);
        f32x4 h0b = *(const f32x4*)(h0 + (size_t)node * D_C + gl * 8 + 4);
        float out[8];
        #pragma unroll
        for (int i = 0; i < 4; i++){
            out[i]     = 0.9f * acc[i]     * ndv + 0.1f * h0a[i];
            out[i + 4] = 0.9f * acc[i + 4] * ndv + 0.1f * h0b[i];
        }
        if (hout){
            f32x4 oa, ob;
            #pragma unroll
            for (int i = 0; i < 4; i++){ oa[i] = out[i]; ob[i] = out[i + 4]; }
            *(f32x4*)(hout + (size_t)node * D_C + gl * 8)     = oa;
            *(f32x4*)(hout + (size_t)node * D_C + gl * 8 + 4) = ob;
        }
        if (houts){
            float nsv = ns[node];
            h16x8 o;
            #pragma unroll
            for (int i = 0; i < 8; i++) o[i] = (_Float16)(out[i] * nsv);
            *(h16x8*)(houts + (size_t)node * D_C + gl * 8) = o;
        }
    }
}

// ---------------- launch ----------------
extern "C" void kernel_launch(void* const* d_in, const int* in_sizes, int n_in,
                              void* d_out, int out_size, void* d_ws, size_t ws_size,
                              hipStream_t stream)
{
    const float* features = (const float*)d_in[0];
    const int*   edge     = (const int*)d_in[1];
    const float* W0 = (const float*)d_in[2];
    const float* b0 = (const float*)d_in[3];
    const float* W1 = (const float*)d_in[4];
    const float* b1 = (const float*)d_in[5];
    const float* W2 = (const float*)d_in[6];
    const float* b2 = (const float*)d_in[7];
    const int* src = edge;
    const int* dst = edge + NE_EDGES;

    char* p = (char*)d_ws;
    auto alloc = [&](size_t bytes) -> char* {
        char* r = p;
        p += (bytes + 255) & ~(size_t)255;
        return r;
    };

    const size_t FEAT  = (size_t)NN_NODES * D_IN * 2;   // 102.4 MB fp16
    const size_t HBUF  = (size_t)NN_NODES * D_C * 4;    // 25.6 MB fp32
    const size_t HBUFH = (size_t)NN_NODES * D_C * 2;    // 12.8 MB fp16

    _Float16* w0f = (_Float16*)alloc((size_t)D_H0 * D_IN * 2);
    _Float16* w1f = (_Float16*)alloc((size_t)D_H1 * D_H0 * 2);
    _Float16* w2f = (_Float16*)alloc((size_t)D_C * D_H1 * 2);
    char* R1 = alloc(FEAT);            // fhf; later act2
    char* R2 = alloc(FEAT);            // act1; later h0 + h0s + hAs + hBs
    int*   deg_out = (int*)alloc((size_t)NN_NODES * 4);
    int*   deg_in  = (int*)alloc((size_t)NN_NODES * 4);
    float* nsrc    = (float*)alloc((size_t)NN_NODES * 4);
    float* ndst    = (float*)alloc((size_t)NN_NODES * 4);
    int*   part    = (int*)alloc((size_t)NN_NODES * 4);
    int*   bsum    = (int*)alloc(2048);
    int*   offs    = (int*)alloc((size_t)NN_NODES * 4);
    int*   cur     = (int*)alloc((size_t)NN_NODES * 4);
    int*   csr     = (int*)alloc((size_t)NE_EDGES * 4);
    if ((size_t)(p - (char*)d_ws) > ws_size) return;

    _Float16* fhf  = (_Float16*)R1;          // dead after GEMM1
    _Float16* act2 = (_Float16*)R1;          // written by GEMM2
    _Float16* act1 = (_Float16*)R2;          // dead after GEMM2
    float*    h0  = (float*)R2;              // written by GEMM3
    _Float16* h0s = (_Float16*)(R2 + HBUF);
    _Float16* hAs = (_Float16*)(R2 + HBUF + HBUFH);
    _Float16* hBs = (_Float16*)(R2 + HBUF + 2 * HBUFH);

    // --- graph preprocessing ---
    hipMemsetAsync(deg_out, 0, (size_t)NN_NODES * 4, stream);
    hipMemsetAsync(deg_in,  0, (size_t)NN_NODES * 4, stream);
    degrees_kernel<<<(NE_EDGES + 255) / 256, 256, 0, stream>>>(src, dst, deg_out, deg_in);
    norm_kernel<<<(NN_NODES + 255) / 256, 256, 0, stream>>>(deg_out, deg_in, nsrc, ndst, NN_NODES);
    int nb = (NN_NODES + 255) / 256;
    scan1_kernel<<<nb, 256, 0, stream>>>(deg_in, part, bsum, NN_NODES);
    scan2_kernel<<<1, 512, 0, stream>>>(bsum, nb);
    scan3_kernel<<<nb, 256, 0, stream>>>(part, deg_in, bsum, offs, cur, NN_NODES);
    fill_kernel<<<(NE_EDGES + 255) / 256, 256, 0, stream>>>(src, dst, cur, csr);

    // --- conversions (fp32 -> fp16) ---
    tof16_kernel<<<(NN_NODES * D_IN / 8 + 255) / 256, 256, 0, stream>>>(
        features, fhf, NN_NODES * D_IN / 8);
    tof16_kernel<<<(D_H0 * D_IN / 8 + 255) / 256, 256, 0, stream>>>(W0, w0f, D_H0 * D_IN / 8);
    tof16_kernel<<<(D_H1 * D_H0 / 8 + 255) / 256, 256, 0, stream>>>(W1, w1f, D_H1 * D_H0 / 8);
    tof16_kernel<<<(D_C * D_H1 / 8 + 255) / 256, 256, 0, stream>>>(W2, w2f, D_C * D_H1 / 8);

    // --- MLP (async register GEMMs, no LDS/barriers) ---
    {   // L0: [100k,512] x [512,512]^T, relu, fp16 out. Block 128x128.
        const int mtiles = (NN_NODES + 127) / 128;   // 782
        int nwg = mtiles * 4;
        gemm_kernel<true, 1, 2, 4, 512><<<nwg, 256, 0, stream>>>(
            fhf, w0f, b0, act1, nullptr, nullptr, NN_NODES, D_H0, nwg / 8, nwg % 8);
    }
    {   // L1: [100k,512] x [256,512]^T, relu, fp16 out. Block 128x128.
        const int mtiles = (NN_NODES + 127) / 128;
        int nwg = mtiles * 2;
        gemm_kernel<true, 1, 2, 2, 512><<<nwg, 256, 0, stream>>>(
            act1, w1f, b1, act2, nullptr, nullptr, NN_NODES, D_H1, nwg / 8, nwg % 8);
    }
    {   // L2: [100k,256] x [64,256]^T, dual out (h0 fp32, h0s=h0*ns fp16). Block 256x64.
        const int mtiles = (NN_NODES + 255) / 256;   // 391
        int nwg = mtiles;
        gemm_kernel<false, 2, 1, 1, 256><<<nwg, 256, 0, stream>>>(
            act2, w2f, b2, h0, h0s, nsrc, NN_NODES, D_C, nwg / 8, nwg % 8);
    }

    // --- APPNP: 10 propagation steps ---
    const _Float16* curs = h0s;
    _Float16* bufss[2] = { hAs, hBs };
    int pb = (NN_NODES + 3) / 4;
    for (int it = 0; it < 10; it++){
        float*    out  = (it == 9) ? (float*)d_out : nullptr;
        _Float16* outs = (it == 9) ? nullptr       : bufss[it & 1];
        propagate_kernel<<<pb, 256, 0, stream>>>(curs, h0, out, outs, offs, deg_in, csr, nsrc, ndst);
        curs = outs;
    }
}

// Round 8
// 882.122 us; speedup vs baseline: 1.2133x; 1.2133x over previous
//
#include <hip/hip_runtime.h>
#include <hip/hip_bf16.h>

#define NN_NODES 100000
#define NE_EDGES 1000000
#define D_IN 512
#define D_H0 512
#define D_H1 256
#define D_C  64

using f32x4  = __attribute__((ext_vector_type(4))) float;
using h16x8  = __attribute__((ext_vector_type(8))) _Float16;

// async global->LDS, 16B/lane; LDS dest = wave-uniform base + lane*16
static __device__ __forceinline__ void gll16(const _Float16* g, _Float16* l){
    __builtin_amdgcn_global_load_lds(
        (const __attribute__((address_space(1))) unsigned int*)g,
        (__attribute__((address_space(3))) unsigned int*)l, 16, 0, 0);
}

// ---------------- fp32 row-major -> fp16 TILED [(R/128)][(K/32)][128x32] ----------------
// Each 8KB slab holds one (m-tile, k-step) staging block, contiguous.
__global__ __launch_bounds__(256) void tof16_tiled_kernel(
    const float* __restrict__ w, _Float16* __restrict__ o, int R, int K)
{
    int i = blockIdx.x * 256 + threadIdx.x;      // 8 elems along a row
    int n8 = R * (K >> 3);
    if (i >= n8) return;
    int kd = K >> 3;
    int r  = i / kd;
    int c0 = (i - r * kd) * 8;
    const f32x4 a = *(const f32x4*)(w + (size_t)r * K + c0);
    const f32x4 b = *(const f32x4*)(w + (size_t)r * K + c0 + 4);
    h16x8 h;
    #pragma unroll
    for (int j = 0; j < 4; j++){
        h[j]   = (_Float16)a[j];
        h[j+4] = (_Float16)b[j];
    }
    size_t off = ((size_t)(r >> 7) * (K >> 5) + (c0 >> 5)) * 4096
               + (size_t)(r & 127) * 32 + (c0 & 31);
    *(h16x8*)(o + off) = h;
}

// ---------------- GEMM: C[M,NNc] = act( A[M,K] * B[NNc,K]^T + bias ) ----------------
// A, B fp16 in TILED layout: slab(mt, t) = ((mt*(K/32)+t)*4096) of [128][32].
// Staging is therefore fully contiguous (1KB per global_load_lds).
// 3-buffer LDS pipeline, counted vmcnt (never 0 in steady loop), raw barriers,
// setprio around MFMA cluster. LDS XOR chunk-swizzle both-sides (conflict-free
// ds_read_b128), identical LDS image to verified round-5 kernel.
// OMODE: 1 fp16 out in TILED layout (for the next GEMM);
//        2 dual row-major out (O1=v fp32, O2=(v*scale[row]) fp16).
template<bool RELU, int OMODE, int BN_T, int NBN, int KK>
__global__ __launch_bounds__(256) void gemm_kernel(
    const _Float16* __restrict__ A,
    const _Float16* __restrict__ B,
    const float* __restrict__ bias,
    void* __restrict__ O1, _Float16* __restrict__ O2, const float* __restrict__ scale,
    int M, int NNc, int xq, int xr)
{
    constexpr int NTK  = KK / 32;          // k-steps
    constexpr int NF   = BN_T / 32;        // n-fragments per wave
    constexpr int BBLK = BN_T / 16;        // 16-row gll blocks per B tile
    constexpr int TOT  = 8 + BBLK;         // gll ops per k-step (A + B)
    constexpr int LPW  = TOT / 4;          // gll ops per wave per stage

    __shared__ _Float16 sA[3][128 * 32];
    __shared__ _Float16 sB[3][BN_T * 32];

    const int tid  = threadIdx.x;
    const int lane = tid & 63;
    const int wv   = tid >> 6;
    const int wm   = wv >> 1;
    const int wn   = wv & 1;

    // bijective XCD-chunk swizzle (m204)
    const int bid = blockIdx.x;
    const int xcd = bid & 7;
    const int i8  = bid >> 3;
    const int L   = ((xcd < xr) ? xcd * (xq + 1) : xr * (xq + 1) + (xcd - xr) * xq) + i8;
    const int mt  = L / NBN;
    const int bn  = L - mt * NBN;
    const int bm0 = mt * 128;
    const int bn0 = bn * BN_T;

    // per-lane constant offset within a 16-row staging block (chunk XOR-swizzled)
    const int loff = (lane >> 2) * 32 + ((lane & 3) ^ ((lane >> 3) & 3)) * 8;

    f32x4 acc[4][NF] = {};

    auto stage = [&](int b, int t){
        const _Float16* as = A + ((size_t)mt * NTK + t) * 4096;
        const _Float16* bs = B + ((size_t)bn * NTK + t) * 4096;
        #pragma unroll
        for (int u = 0; u < LPW; u++){
            int idx = u * 4 + wv;
            if (idx < 8) gll16(as + idx * 512 + loff, sA[b] + idx * 512);
            else         gll16(bs + (idx - 8) * 512 + loff, sB[b] + (idx - 8) * 512);
        }
    };

    auto compute = [&](int b){
        const int fr = lane & 15;
        const int fc = lane >> 4;
        h16x8 bf[NF];
        #pragma unroll
        for (int nf = 0; nf < NF; nf++){
            int r = wn * (BN_T / 2) + nf * 16 + fr;
            int c = (fc ^ ((r >> 1) & 3)) * 8;
            bf[nf] = *(const h16x8*)&sB[b][r * 32 + c];
        }
        h16x8 af[4];
        #pragma unroll
        for (int mf = 0; mf < 4; mf++){
            int r = wm * 64 + mf * 16 + fr;
            int c = (fc ^ ((r >> 1) & 3)) * 8;
            af[mf] = *(const h16x8*)&sA[b][r * 32 + c];
        }
        __builtin_amdgcn_s_setprio(1);
        #pragma unroll
        for (int mf = 0; mf < 4; mf++)
            #pragma unroll
            for (int nf = 0; nf < NF; nf++)
                acc[mf][nf] = __builtin_amdgcn_mfma_f32_16x16x32_f16(af[mf], bf[nf], acc[mf][nf], 0, 0, 0);
        __builtin_amdgcn_s_setprio(0);
    };

    stage(0, 0);
    stage(1, 1);
    for (int t = 0; t < NTK; t++){
        if (t + 2 < NTK){
            stage((t + 2) % 3, t + 2);
            // wait for tile t's loads only; 2 stages (2*LPW) stay in flight
            if constexpr (LPW == 4) asm volatile("s_waitcnt vmcnt(8)" ::: "memory");
            else                    asm volatile("s_waitcnt vmcnt(6)" ::: "memory");
        } else if (t + 1 < NTK){
            if constexpr (LPW == 4) asm volatile("s_waitcnt vmcnt(4)" ::: "memory");
            else                    asm volatile("s_waitcnt vmcnt(3)" ::: "memory");
        } else {
            asm volatile("s_waitcnt vmcnt(0)" ::: "memory");
        }
        __builtin_amdgcn_s_barrier();       // buf[t%3] complete for all waves
        asm volatile("" ::: "memory");
        compute(t % 3);
        asm volatile("" ::: "memory");
        __builtin_amdgcn_s_barrier();       // all reads of buf[t%3] retired
        asm volatile("" ::: "memory");
    }

    // ---- epilogue ----
    #pragma unroll
    for (int mf = 0; mf < 4; mf++){
        #pragma unroll
        for (int nf = 0; nf < NF; nf++){
            #pragma unroll
            for (int r = 0; r < 4; r++){
                int rg = bm0 + wm * 64 + mf * 16 + (lane >> 4) * 4 + r;
                int cg = bn0 + wn * (BN_T / 2) + nf * 16 + (lane & 15);
                if (rg < M){
                    float v = acc[mf][nf][r] + bias[cg];
                    if constexpr (RELU) v = fmaxf(v, 0.f);
                    if constexpr (OMODE == 1){
                        // tiled activation write for the next GEMM's staging
                        size_t o = ((size_t)mt * (NNc >> 5) + (cg >> 5)) * 4096
                                 + (size_t)(rg & 127) * 32 + (cg & 31);
                        ((_Float16*)O1)[o] = (_Float16)v;
                    } else {
                        ((float*)O1)[(size_t)rg * NNc + cg] = v;
                        O2[(size_t)rg * NNc + cg] = (_Float16)(v * scale[rg]);
                    }
                }
            }
        }
    }
}

// ---------------- graph preprocessing ----------------
__global__ void degrees_kernel(const int* __restrict__ src, const int* __restrict__ dst,
                               int* __restrict__ dout, int* __restrict__ din){
    int e = blockIdx.x * blockDim.x + threadIdx.x;
    if (e < NE_EDGES){
        atomicAdd(&dout[src[e]], 1);
        atomicAdd(&din[dst[e]], 1);
    }
}

__global__ void norm_kernel(const int* __restrict__ dout, const int* __restrict__ din,
                            float* __restrict__ ns, float* __restrict__ nd, int n){
    int i = blockIdx.x * blockDim.x + threadIdx.x;
    if (i < n){
        ns[i] = rsqrtf((float)(dout[i] > 1 ? dout[i] : 1));
        nd[i] = rsqrtf((float)(din[i]  > 1 ? din[i]  : 1));
    }
}

__global__ __launch_bounds__(256) void scan1_kernel(const int* __restrict__ din,
                                                    int* __restrict__ part,
                                                    int* __restrict__ bsum, int n){
    __shared__ int s[256];
    int i = blockIdx.x * 256 + threadIdx.x;
    int v = (i < n) ? din[i] : 0;
    s[threadIdx.x] = v;
    __syncthreads();
    for (int off = 1; off < 256; off <<= 1){
        int t = (threadIdx.x >= off) ? s[threadIdx.x - off] : 0;
        __syncthreads();
        s[threadIdx.x] += t;
        __syncthreads();
    }
    if (i < n) part[i] = s[threadIdx.x];
    if (threadIdx.x == 255) bsum[blockIdx.x] = s[255];
}

__global__ __launch_bounds__(512) void scan2_kernel(int* __restrict__ bsum, int nb){
    __shared__ int s[512];
    int v = (threadIdx.x < nb) ? bsum[threadIdx.x] : 0;
    s[threadIdx.x] = v;
    __syncthreads();
    for (int off = 1; off < 512; off <<= 1){
        int t = (threadIdx.x >= off) ? s[threadIdx.x - off] : 0;
        __syncthreads();
        s[threadIdx.x] += t;
        __syncthreads();
    }
    if (threadIdx.x < nb) bsum[threadIdx.x] = s[threadIdx.x];
}

__global__ void scan3_kernel(const int* __restrict__ part, const int* __restrict__ din,
                             const int* __restrict__ bsum, int* __restrict__ offs,
                             int* __restrict__ cur, int n){
    int i = blockIdx.x * 256 + threadIdx.x;
    if (i < n){
        int base = (blockIdx.x > 0) ? bsum[blockIdx.x - 1] : 0;
        int excl = base + part[i] - din[i];
        offs[i] = excl;
        cur[i]  = excl;
    }
}

__global__ void fill_kernel(const int* __restrict__ src, const int* __restrict__ dst,
                            int* __restrict__ cur, int* __restrict__ csr){
    int e = blockIdx.x * blockDim.x + threadIdx.x;
    if (e < NE_EDGES){
        int d = dst[e];
        int pos = atomicAdd(&cur[d], 1);
        csr[pos] = src[e];
    }
}

// ---------------- APPNP propagation (fp16 gather state) ----------------
__global__ __launch_bounds__(256) void propagate_kernel(
    const _Float16* __restrict__ hs, const float* __restrict__ h0,
    float* __restrict__ hout, _Float16* __restrict__ houts,
    const int* __restrict__ offs, const int* __restrict__ din,
    const int* __restrict__ csr,
    const float* __restrict__ ns, const float* __restrict__ nd)
{
    int wv   = threadIdx.x >> 6;
    int lane = threadIdx.x & 63;
    int grp  = lane >> 3;     // 0..7
    int gl   = lane & 7;      // 0..7
    int node = blockIdx.x * 4 + wv;
    if (node >= NN_NODES) return;
    int start = offs[node];
    int deg   = din[node];
    float acc[8] = {};
    for (int j = grp; j < deg; j += 8){
        int s = csr[start + j];
        h16x8 v = *(const h16x8*)(hs + (size_t)s * D_C + gl * 8);
        #pragma unroll
        for (int i = 0; i < 8; i++) acc[i] += (float)v[i];
    }
    #pragma unroll
    for (int i = 0; i < 8; i++){
        acc[i] += __shfl_xor(acc[i], 8, 64);
        acc[i] += __shfl_xor(acc[i], 16, 64);
        acc[i] += __shfl_xor(acc[i], 32, 64);
    }
    if (grp == 0){
        float ndv = nd[node];
        f32x4 h0a = *(const f32x4*)(h0 + (size_t)node * D_C + gl * 8);
        f32x4 h0b = *(const f32x4*)(h0 + (size_t)node * D_C + gl * 8 + 4);
        float out[8];
        #pragma unroll
        for (int i = 0; i < 4; i++){
            out[i]     = 0.9f * acc[i]     * ndv + 0.1f * h0a[i];
            out[i + 4] = 0.9f * acc[i + 4] * ndv + 0.1f * h0b[i];
        }
        if (hout){
            f32x4 oa, ob;
            #pragma unroll
            for (int i = 0; i < 4; i++){ oa[i] = out[i]; ob[i] = out[i + 4]; }
            *(f32x4*)(hout + (size_t)node * D_C + gl * 8)     = oa;
            *(f32x4*)(hout + (size_t)node * D_C + gl * 8 + 4) = ob;
        }
        if (houts){
            float nsv = ns[node];
            h16x8 o;
            #pragma unroll
            for (int i = 0; i < 8; i++) o[i] = (_Float16)(out[i] * nsv);
            *(h16x8*)(houts + (size_t)node * D_C + gl * 8) = o;
        }
    }
}

// ---------------- launch ----------------
extern "C" void kernel_launch(void* const* d_in, const int* in_sizes, int n_in,
                              void* d_out, int out_size, void* d_ws, size_t ws_size,
                              hipStream_t stream)
{
    const float* features = (const float*)d_in[0];
    const int*   edge     = (const int*)d_in[1];
    const float* W0 = (const float*)d_in[2];
    const float* b0 = (const float*)d_in[3];
    const float* W1 = (const float*)d_in[4];
    const float* b1 = (const float*)d_in[5];
    const float* W2 = (const float*)d_in[6];
    const float* b2 = (const float*)d_in[7];
    const int* src = edge;
    const int* dst = edge + NE_EDGES;

    char* p = (char*)d_ws;
    auto alloc = [&](size_t bytes) -> char* {
        char* r = p;
        p += (bytes + 255) & ~(size_t)255;
        return r;
    };

    const int MT = (NN_NODES + 127) / 128;              // 782 m-tiles
    const size_t FEAT_T = (size_t)MT * 16 * 4096 * 2;   // tiled fp16, K=512 (102.5 MB)
    const size_t ACT2_T = (size_t)MT * 8 * 4096 * 2;    // tiled fp16, K=256 (51.3 MB)
    const size_t HBUF   = (size_t)NN_NODES * D_C * 4;   // 25.6 MB fp32
    const size_t HBUFH  = (size_t)NN_NODES * D_C * 2;   // 12.8 MB fp16

    _Float16* w0f = (_Float16*)alloc((size_t)4 * 16 * 4096 * 2);  // 512 rows
    _Float16* w1f = (_Float16*)alloc((size_t)2 * 16 * 4096 * 2);  // 256 rows
    _Float16* w2f = (_Float16*)alloc((size_t)1 * 8  * 4096 * 2);  // 64 rows (half slab used)
    char* R1 = alloc(FEAT_T);          // fhf (tiled); later act2 (tiled)
    char* R2 = alloc(FEAT_T);          // act1 (tiled); later h0 + h0s + hAs + hBs
    int*   deg_out = (int*)alloc((size_t)NN_NODES * 4);
    int*   deg_in  = (int*)alloc((size_t)NN_NODES * 4);
    float* nsrc    = (float*)alloc((size_t)NN_NODES * 4);
    float* ndst    = (float*)alloc((size_t)NN_NODES * 4);
    int*   part    = (int*)alloc((size_t)NN_NODES * 4);
    int*   bsum    = (int*)alloc(2048);
    int*   offs    = (int*)alloc((size_t)NN_NODES * 4);
    int*   cur     = (int*)alloc((size_t)NN_NODES * 4);
    int*   csr     = (int*)alloc((size_t)NE_EDGES * 4);
    if ((size_t)(p - (char*)d_ws) > ws_size) return;

    _Float16* fhf  = (_Float16*)R1;          // dead after GEMM1
    _Float16* act2 = (_Float16*)R1;          // written by GEMM2 (tiled)
    _Float16* act1 = (_Float16*)R2;          // dead after GEMM2
    float*    h0  = (float*)R2;              // written by GEMM3 (row-major)
    _Float16* h0s = (_Float16*)(R2 + HBUF);
    _Float16* hAs = (_Float16*)(R2 + HBUF + HBUFH);
    _Float16* hBs = (_Float16*)(R2 + HBUF + 2 * HBUFH);
    (void)ACT2_T;

    // --- graph preprocessing ---
    hipMemsetAsync(deg_out, 0, (size_t)NN_NODES * 4, stream);
    hipMemsetAsync(deg_in,  0, (size_t)NN_NODES * 4, stream);
    degrees_kernel<<<(NE_EDGES + 255) / 256, 256, 0, stream>>>(src, dst, deg_out, deg_in);
    norm_kernel<<<(NN_NODES + 255) / 256, 256, 0, stream>>>(deg_out, deg_in, nsrc, ndst, NN_NODES);
    int nb = (NN_NODES + 255) / 256;
    scan1_kernel<<<nb, 256, 0, stream>>>(deg_in, part, bsum, NN_NODES);
    scan2_kernel<<<1, 512, 0, stream>>>(bsum, nb);
    scan3_kernel<<<nb, 256, 0, stream>>>(part, deg_in, bsum, offs, cur, NN_NODES);
    fill_kernel<<<(NE_EDGES + 255) / 256, 256, 0, stream>>>(src, dst, cur, csr);

    // --- conversions (fp32 row-major -> fp16 tiled) ---
    tof16_tiled_kernel<<<(NN_NODES * D_IN / 8 + 255) / 256, 256, 0, stream>>>(
        features, fhf, NN_NODES, D_IN);
    tof16_tiled_kernel<<<(D_H0 * D_IN / 8 + 255) / 256, 256, 0, stream>>>(W0, w0f, D_H0, D_IN);
    tof16_tiled_kernel<<<(D_H1 * D_H0 / 8 + 255) / 256, 256, 0, stream>>>(W1, w1f, D_H1, D_H0);
    tof16_tiled_kernel<<<(D_C * D_H1 / 8 + 255) / 256, 256, 0, stream>>>(W2, w2f, D_C, D_H1);

    // --- MLP ---
    {   // L0: [100k,512] x [512,512]^T, relu, tiled fp16 out
        int nwg = MT * 4;
        gemm_kernel<true, 1, 128, 4, 512><<<nwg, 256, 0, stream>>>(
            fhf, w0f, b0, act1, nullptr, nullptr, NN_NODES, D_H0, nwg / 8, nwg % 8);
    }
    {   // L1: [100k,512] x [256,512]^T, relu, tiled fp16 out
        int nwg = MT * 2;
        gemm_kernel<true, 1, 128, 2, 512><<<nwg, 256, 0, stream>>>(
            act1, w1f, b1, act2, nullptr, nullptr, NN_NODES, D_H1, nwg / 8, nwg % 8);
    }
    {   // L2: [100k,256] x [64,256]^T, dual row-major out (h0 fp32, h0s=h0*ns fp16)
        int nwg = MT;
        gemm_kernel<false, 2, 64, 1, 256><<<nwg, 256, 0, stream>>>(
            act2, w2f, b2, h0, h0s, nsrc, NN_NODES, D_C, nwg / 8, nwg % 8);
    }

    // --- APPNP: 10 propagation steps ---
    const _Float16* curs = h0s;
    _Float16* bufss[2] = { hAs, hBs };
    int pb = (NN_NODES + 3) / 4;
    for (int it = 0; it < 10; it++){
        float*    out  = (it == 9) ? (float*)d_out : nullptr;
        _Float16* outs = (it == 9) ? nullptr       : bufss[it & 1];
        propagate_kernel<<<pb, 256, 0, stream>>>(curs, h0, out, outs, offs, deg_in, csr, nsrc, ndst);
        curs = outs;
    }
}

// Round 9
// 814.454 us; speedup vs baseline: 1.3141x; 1.0831x over previous
//
#include <hip/hip_runtime.h>
#include <hip/hip_bf16.h>

#define NN_NODES 100000
#define NE_EDGES 1000000
#define D_IN 512
#define D_H0 512
#define D_H1 256
#define D_C  64

using f32x4  = __attribute__((ext_vector_type(4))) float;
using h16x8  = __attribute__((ext_vector_type(8))) _Float16;

// async global->LDS, 16B/lane; LDS dest = wave-uniform base + lane*16
static __device__ __forceinline__ void gll16(const _Float16* g, _Float16* l){
    __builtin_amdgcn_global_load_lds(
        (const __attribute__((address_space(1))) unsigned int*)g,
        (__attribute__((address_space(3))) unsigned int*)l, 16, 0, 0);
}

// ---------------- fp32 row-major -> fp16 TILED [(R/128)][(K/32)][128x32] ----------------
__global__ __launch_bounds__(256) void tof16_tiled_kernel(
    const float* __restrict__ w, _Float16* __restrict__ o, int R, int K)
{
    int i = blockIdx.x * 256 + threadIdx.x;      // 8 elems along a row
    int n8 = R * (K >> 3);
    if (i >= n8) return;
    int kd = K >> 3;
    int r  = i / kd;
    int c0 = (i - r * kd) * 8;
    const f32x4 a = *(const f32x4*)(w + (size_t)r * K + c0);
    const f32x4 b = *(const f32x4*)(w + (size_t)r * K + c0 + 4);
    h16x8 h;
    #pragma unroll
    for (int j = 0; j < 4; j++){
        h[j]   = (_Float16)a[j];
        h[j+4] = (_Float16)b[j];
    }
    size_t off = ((size_t)(r >> 7) * (K >> 5) + (c0 >> 5)) * 4096
               + (size_t)(r & 127) * 32 + (c0 & 31);
    *(h16x8*)(o + off) = h;
}

// ---------------- GEMM: C[M,NNc] = act( A[M,K] * B[NNc,K]^T + bias ) ----------------
// A, B fp16 in TILED layout: slab(rowblk, t) at ((rowblk*(K/32)+t)*4096), [128][32].
// 2-buffer LDS + __syncthreads (round-5 proven structure), tiled contiguous
// staging, XOR chunk-swizzle both-sides (0 bank conflicts).
// __launch_bounds__(256,4): force total regs <= 128 -> 4 waves/SIMD (the
// occupancy bucket fix; was 132+ regs -> 2 waves/SIMD -> 25% occupancy).
// OMODE: 1 fp16 out in TILED layout; 2 dual row-major out (fp32 + *scale fp16).
template<bool RELU, int OMODE, int BN_T, int NBN, int KK>
__global__ __launch_bounds__(256, 4) void gemm_kernel(
    const _Float16* __restrict__ A,
    const _Float16* __restrict__ B,
    const float* __restrict__ bias,
    void* __restrict__ O1, _Float16* __restrict__ O2, const float* __restrict__ scale,
    int M, int NNc, int xq, int xr)
{
    constexpr int NTK  = KK / 32;          // k-steps
    constexpr int NF   = BN_T / 32;        // n-fragments per wave
    constexpr int BBLK = BN_T / 16;        // 16-row gll blocks per B tile
    constexpr int TOT  = 8 + BBLK;         // gll ops per k-step (A + B)
    constexpr int LPW  = TOT / 4;          // gll ops per wave per stage

    __shared__ _Float16 sA[2][128 * 32];
    __shared__ _Float16 sB[2][BN_T * 32];

    const int tid  = threadIdx.x;
    const int lane = tid & 63;
    const int wv   = tid >> 6;
    const int wm   = wv >> 1;
    const int wn   = wv & 1;

    // bijective XCD-chunk swizzle (m204)
    const int bid = blockIdx.x;
    const int xcd = bid & 7;
    const int i8  = bid >> 3;
    const int L   = ((xcd < xr) ? xcd * (xq + 1) : xr * (xq + 1) + (xcd - xr) * xq) + i8;
    const int mt  = L / NBN;
    const int bn  = L - mt * NBN;
    const int bm0 = mt * 128;
    const int bn0 = bn * BN_T;

    // per-lane constant offset within a 16-row staging block (chunk XOR-swizzled)
    const int loff = (lane >> 2) * 32 + ((lane & 3) ^ ((lane >> 3) & 3)) * 8;

    f32x4 acc[4][NF] = {};

    auto stage = [&](int b, int t){
        const _Float16* as = A + ((size_t)mt * NTK + t) * 4096;
        const _Float16* bs = B + ((size_t)bn * NTK + t) * 4096;
        #pragma unroll
        for (int u = 0; u < LPW; u++){
            int idx = u * 4 + wv;
            if (idx < 8) gll16(as + idx * 512 + loff, sA[b] + idx * 512);
            else         gll16(bs + (idx - 8) * 512 + loff, sB[b] + (idx - 8) * 512);
        }
    };

    auto compute = [&](int b){
        const int fr = lane & 15;
        const int fc = lane >> 4;
        h16x8 bf[NF];
        #pragma unroll
        for (int nf = 0; nf < NF; nf++){
            int r = wn * (BN_T / 2) + nf * 16 + fr;
            int c = (fc ^ ((r >> 1) & 3)) * 8;
            bf[nf] = *(const h16x8*)&sB[b][r * 32 + c];
        }
        h16x8 af[4];
        #pragma unroll
        for (int mf = 0; mf < 4; mf++){
            int r = wm * 64 + mf * 16 + fr;
            int c = (fc ^ ((r >> 1) & 3)) * 8;
            af[mf] = *(const h16x8*)&sA[b][r * 32 + c];
        }
        __builtin_amdgcn_s_setprio(1);
        #pragma unroll
        for (int mf = 0; mf < 4; mf++)
            #pragma unroll
            for (int nf = 0; nf < NF; nf++)
                acc[mf][nf] = __builtin_amdgcn_mfma_f32_16x16x32_f16(af[mf], bf[nf], acc[mf][nf], 0, 0, 0);
        __builtin_amdgcn_s_setprio(0);
    };

    stage(0, 0);
    __syncthreads();
    int cur = 0;
    for (int t = 0; t < NTK; t++){
        if (t + 1 < NTK) stage(cur ^ 1, t + 1);
        compute(cur);
        __syncthreads();
        cur ^= 1;
    }

    // ---- epilogue ----
    #pragma unroll
    for (int mf = 0; mf < 4; mf++){
        #pragma unroll
        for (int nf = 0; nf < NF; nf++){
            #pragma unroll
            for (int r = 0; r < 4; r++){
                int rg = bm0 + wm * 64 + mf * 16 + (lane >> 4) * 4 + r;
                int cg = bn0 + wn * (BN_T / 2) + nf * 16 + (lane & 15);
                if (rg < M){
                    float v = acc[mf][nf][r] + bias[cg];
                    if constexpr (RELU) v = fmaxf(v, 0.f);
                    if constexpr (OMODE == 1){
                        size_t o = ((size_t)mt * (NNc >> 5) + (cg >> 5)) * 4096
                                 + (size_t)(rg & 127) * 32 + (cg & 31);
                        ((_Float16*)O1)[o] = (_Float16)v;
                    } else {
                        ((float*)O1)[(size_t)rg * NNc + cg] = v;
                        O2[(size_t)rg * NNc + cg] = (_Float16)(v * scale[rg]);
                    }
                }
            }
        }
    }
}

// ---------------- graph preprocessing ----------------
__global__ void degrees_kernel(const int* __restrict__ src, const int* __restrict__ dst,
                               int* __restrict__ dout, int* __restrict__ din){
    int e = blockIdx.x * blockDim.x + threadIdx.x;
    if (e < NE_EDGES){
        atomicAdd(&dout[src[e]], 1);
        atomicAdd(&din[dst[e]], 1);
    }
}

__global__ void norm_kernel(const int* __restrict__ dout, const int* __restrict__ din,
                            float* __restrict__ ns, float* __restrict__ nd, int n){
    int i = blockIdx.x * blockDim.x + threadIdx.x;
    if (i < n){
        ns[i] = rsqrtf((float)(dout[i] > 1 ? dout[i] : 1));
        nd[i] = rsqrtf((float)(din[i]  > 1 ? din[i]  : 1));
    }
}

__global__ __launch_bounds__(256) void scan1_kernel(const int* __restrict__ din,
                                                    int* __restrict__ part,
                                                    int* __restrict__ bsum, int n){
    __shared__ int s[256];
    int i = blockIdx.x * 256 + threadIdx.x;
    int v = (i < n) ? din[i] : 0;
    s[threadIdx.x] = v;
    __syncthreads();
    for (int off = 1; off < 256; off <<= 1){
        int t = (threadIdx.x >= off) ? s[threadIdx.x - off] : 0;
        __syncthreads();
        s[threadIdx.x] += t;
        __syncthreads();
    }
    if (i < n) part[i] = s[threadIdx.x];
    if (threadIdx.x == 255) bsum[blockIdx.x] = s[255];
}

__global__ __launch_bounds__(512) void scan2_kernel(int* __restrict__ bsum, int nb){
    __shared__ int s[512];
    int v = (threadIdx.x < nb) ? bsum[threadIdx.x] : 0;
    s[threadIdx.x] = v;
    __syncthreads();
    for (int off = 1; off < 512; off <<= 1){
        int t = (threadIdx.x >= off) ? s[threadIdx.x - off] : 0;
        __syncthreads();
        s[threadIdx.x] += t;
        __syncthreads();
    }
    if (threadIdx.x < nb) bsum[threadIdx.x] = s[threadIdx.x];
}

__global__ void scan3_kernel(const int* __restrict__ part, const int* __restrict__ din,
                             const int* __restrict__ bsum, int* __restrict__ offs,
                             int* __restrict__ cur, int n){
    int i = blockIdx.x * 256 + threadIdx.x;
    if (i < n){
        int base = (blockIdx.x > 0) ? bsum[blockIdx.x - 1] : 0;
        int excl = base + part[i] - din[i];
        offs[i] = excl;
        cur[i]  = excl;
    }
}

__global__ void fill_kernel(const int* __restrict__ src, const int* __restrict__ dst,
                            int* __restrict__ cur, int* __restrict__ csr){
    int e = blockIdx.x * blockDim.x + threadIdx.x;
    if (e < NE_EDGES){
        int d = dst[e];
        int pos = atomicAdd(&cur[d], 1);
        csr[pos] = src[e];
    }
}

// ---------------- APPNP propagation (fp16 gather state) ----------------
__global__ __launch_bounds__(256) void propagate_kernel(
    const _Float16* __restrict__ hs, const float* __restrict__ h0,
    float* __restrict__ hout, _Float16* __restrict__ houts,
    const int* __restrict__ offs, const int* __restrict__ din,
    const int* __restrict__ csr,
    const float* __restrict__ ns, const float* __restrict__ nd)
{
    int wv   = threadIdx.x >> 6;
    int lane = threadIdx.x & 63;
    int grp  = lane >> 3;     // 0..7
    int gl   = lane & 7;      // 0..7
    int node = blockIdx.x * 4 + wv;
    if (node >= NN_NODES) return;
    int start = offs[node];
    int deg   = din[node];
    // pre-issue independent h0 row load (grp 0 only consumes it)
    f32x4 h0a = {}, h0b = {};
    if (grp == 0){
        h0a = *(const f32x4*)(h0 + (size_t)node * D_C + gl * 8);
        h0b = *(const f32x4*)(h0 + (size_t)node * D_C + gl * 8 + 4);
    }
    float acc[8] = {};
    for (int j = grp; j < deg; j += 8){
        int s = csr[start + j];
        h16x8 v = *(const h16x8*)(hs + (size_t)s * D_C + gl * 8);
        #pragma unroll
        for (int i = 0; i < 8; i++) acc[i] += (float)v[i];
    }
    #pragma unroll
    for (int i = 0; i < 8; i++){
        acc[i] += __shfl_xor(acc[i], 8, 64);
        acc[i] += __shfl_xor(acc[i], 16, 64);
        acc[i] += __shfl_xor(acc[i], 32, 64);
    }
    if (grp == 0){
        float ndv = nd[node];
        float out[8];
        #pragma unroll
        for (int i = 0; i < 4; i++){
            out[i]     = 0.9f * acc[i]     * ndv + 0.1f * h0a[i];
            out[i + 4] = 0.9f * acc[i + 4] * ndv + 0.1f * h0b[i];
        }
        if (hout){
            f32x4 oa, ob;
            #pragma unroll
            for (int i = 0; i < 4; i++){ oa[i] = out[i]; ob[i] = out[i + 4]; }
            *(f32x4*)(hout + (size_t)node * D_C + gl * 8)     = oa;
            *(f32x4*)(hout + (size_t)node * D_C + gl * 8 + 4) = ob;
        }
        if (houts){
            float nsv = ns[node];
            h16x8 o;
            #pragma unroll
            for (int i = 0; i < 8; i++) o[i] = (_Float16)(out[i] * nsv);
            *(h16x8*)(houts + (size_t)node * D_C + gl * 8) = o;
        }
    }
}

// ---------------- launch ----------------
extern "C" void kernel_launch(void* const* d_in, const int* in_sizes, int n_in,
                              void* d_out, int out_size, void* d_ws, size_t ws_size,
                              hipStream_t stream)
{
    const float* features = (const float*)d_in[0];
    const int*   edge     = (const int*)d_in[1];
    const float* W0 = (const float*)d_in[2];
    const float* b0 = (const float*)d_in[3];
    const float* W1 = (const float*)d_in[4];
    const float* b1 = (const float*)d_in[5];
    const float* W2 = (const float*)d_in[6];
    const float* b2 = (const float*)d_in[7];
    const int* src = edge;
    const int* dst = edge + NE_EDGES;

    char* p = (char*)d_ws;
    auto alloc = [&](size_t bytes) -> char* {
        char* r = p;
        p += (bytes + 255) & ~(size_t)255;
        return r;
    };

    const int MT = (NN_NODES + 127) / 128;              // 782 m-tiles
    const size_t FEAT_T = (size_t)MT * 16 * 4096 * 2;   // tiled fp16, K=512
    const size_t HBUF   = (size_t)NN_NODES * D_C * 4;   // 25.6 MB fp32
    const size_t HBUFH  = (size_t)NN_NODES * D_C * 2;   // 12.8 MB fp16

    _Float16* w0f = (_Float16*)alloc((size_t)4 * 16 * 4096 * 2);  // 512 rows
    _Float16* w1f = (_Float16*)alloc((size_t)2 * 16 * 4096 * 2);  // 256 rows
    _Float16* w2f = (_Float16*)alloc((size_t)1 * 8  * 4096 * 2);  // 64 rows
    char* R1 = alloc(FEAT_T);          // fhf (tiled); later act2 (tiled)
    char* R2 = alloc(FEAT_T);          // act1 (tiled); later h0 + h0s + hAs + hBs
    int*   deg_out = (int*)alloc((size_t)NN_NODES * 4);
    int*   deg_in  = (int*)alloc((size_t)NN_NODES * 4);
    float* nsrc    = (float*)alloc((size_t)NN_NODES * 4);
    float* ndst    = (float*)alloc((size_t)NN_NODES * 4);
    int*   part    = (int*)alloc((size_t)NN_NODES * 4);
    int*   bsum    = (int*)alloc(2048);
    int*   offs    = (int*)alloc((size_t)NN_NODES * 4);
    int*   cur     = (int*)alloc((size_t)NN_NODES * 4);
    int*   csr     = (int*)alloc((size_t)NE_EDGES * 4);
    if ((size_t)(p - (char*)d_ws) > ws_size) return;

    _Float16* fhf  = (_Float16*)R1;          // dead after GEMM1
    _Float16* act2 = (_Float16*)R1;          // written by GEMM2 (tiled)
    _Float16* act1 = (_Float16*)R2;          // dead after GEMM2
    float*    h0  = (float*)R2;              // written by GEMM3 (row-major)
    _Float16* h0s = (_Float16*)(R2 + HBUF);
    _Float16* hAs = (_Float16*)(R2 + HBUF + HBUFH);
    _Float16* hBs = (_Float16*)(R2 + HBUF + 2 * HBUFH);

    // --- graph preprocessing ---
    hipMemsetAsync(deg_out, 0, (size_t)NN_NODES * 4, stream);
    hipMemsetAsync(deg_in,  0, (size_t)NN_NODES * 4, stream);
    degrees_kernel<<<(NE_EDGES + 255) / 256, 256, 0, stream>>>(src, dst, deg_out, deg_in);
    norm_kernel<<<(NN_NODES + 255) / 256, 256, 0, stream>>>(deg_out, deg_in, nsrc, ndst, NN_NODES);
    int nb = (NN_NODES + 255) / 256;
    scan1_kernel<<<nb, 256, 0, stream>>>(deg_in, part, bsum, NN_NODES);
    scan2_kernel<<<1, 512, 0, stream>>>(bsum, nb);
    scan3_kernel<<<nb, 256, 0, stream>>>(part, deg_in, bsum, offs, cur, NN_NODES);
    fill_kernel<<<(NE_EDGES + 255) / 256, 256, 0, stream>>>(src, dst, cur, csr);

    // --- conversions (fp32 row-major -> fp16 tiled) ---
    tof16_tiled_kernel<<<(NN_NODES * D_IN / 8 + 255) / 256, 256, 0, stream>>>(
        features, fhf, NN_NODES, D_IN);
    tof16_tiled_kernel<<<(D_H0 * D_IN / 8 + 255) / 256, 256, 0, stream>>>(W0, w0f, D_H0, D_IN);
    tof16_tiled_kernel<<<(D_H1 * D_H0 / 8 + 255) / 256, 256, 0, stream>>>(W1, w1f, D_H1, D_H0);
    tof16_tiled_kernel<<<(D_C * D_H1 / 8 + 255) / 256, 256, 0, stream>>>(W2, w2f, D_C, D_H1);

    // --- MLP ---
    {   // L0: [100k,512] x [512,512]^T, relu, tiled fp16 out
        int nwg = MT * 4;
        gemm_kernel<true, 1, 128, 4, 512><<<nwg, 256, 0, stream>>>(
            fhf, w0f, b0, act1, nullptr, nullptr, NN_NODES, D_H0, nwg / 8, nwg % 8);
    }
    {   // L1: [100k,512] x [256,512]^T, relu, tiled fp16 out
        int nwg = MT * 2;
        gemm_kernel<true, 1, 128, 2, 512><<<nwg, 256, 0, stream>>>(
            act1, w1f, b1, act2, nullptr, nullptr, NN_NODES, D_H1, nwg / 8, nwg % 8);
    }
    {   // L2: [100k,256] x [64,256]^T, dual row-major out (h0 fp32, h0s=h0*ns fp16)
        int nwg = MT;
        gemm_kernel<false, 2, 64, 1, 256><<<nwg, 256, 0, stream>>>(
            act2, w2f, b2, h0, h0s, nsrc, NN_NODES, D_C, nwg / 8, nwg % 8);
    }

    // --- APPNP: 10 propagation steps ---
    const _Float16* curs = h0s;
    _Float16* bufss[2] = { hAs, hBs };
    int pb = (NN_NODES + 3) / 4;
    for (int it = 0; it < 10; it++){
        float*    out  = (it == 9) ? (float*)d_out : nullptr;
        _Float16* outs = (it == 9) ? nullptr       : bufss[it & 1];
        propagate_kernel<<<pb, 256, 0, stream>>>(curs, h0, out, outs, offs, deg_in, csr, nsrc, ndst);
        curs = outs;
    }
}

// Round 10
// 769.758 us; speedup vs baseline: 1.3904x; 1.0581x over previous
//
#include <hip/hip_runtime.h>
#include <hip/hip_bf16.h>

#define NN_NODES 100000
#define NE_EDGES 1000000
#define D_IN 512
#define D_H0 512
#define D_H1 256
#define D_C  64

using f32x4  = __attribute__((ext_vector_type(4))) float;
using h16x8  = __attribute__((ext_vector_type(8))) _Float16;

// async global->LDS, 16B/lane; LDS dest = wave-uniform base + lane*16
static __device__ __forceinline__ void gll16(const _Float16* g, _Float16* l){
    __builtin_amdgcn_global_load_lds(
        (const __attribute__((address_space(1))) unsigned int*)g,
        (__attribute__((address_space(3))) unsigned int*)l, 16, 0, 0);
}

// ---------------- fp32 row-major -> fp16 TILED [(R/128)][(K/32)][128x32] ----------------
__global__ __launch_bounds__(256) void tof16_tiled_kernel(
    const float* __restrict__ w, _Float16* __restrict__ o, int R, int K)
{
    int i = blockIdx.x * 256 + threadIdx.x;      // 8 elems along a row
    int n8 = R * (K >> 3);
    if (i >= n8) return;
    int kd = K >> 3;
    int r  = i / kd;
    int c0 = (i - r * kd) * 8;
    const f32x4 a = *(const f32x4*)(w + (size_t)r * K + c0);
    const f32x4 b = *(const f32x4*)(w + (size_t)r * K + c0 + 4);
    h16x8 h;
    #pragma unroll
    for (int j = 0; j < 4; j++){
        h[j]   = (_Float16)a[j];
        h[j+4] = (_Float16)b[j];
    }
    size_t off = ((size_t)(r >> 7) * (K >> 5) + (c0 >> 5)) * 4096
               + (size_t)(r & 127) * 32 + (c0 & 31);
    *(h16x8*)(o + off) = h;
}

// ---------------- GEMM: C[M,NNc] = act( A[M,K] * B[NNc,K]^T + bias ) ----------------
// A fp16 tiled, staged to LDS via gll (3 buffers, depth-2 counted vmcnt).
// B fp16 tiled, consumed DIRECTLY global->reg (L2-resident weights), double-
// buffered; tiled layout makes each fragment load a contiguous 1KB per wave.
// Issue order per k-step: loadB(t+1), stageA(t+2), s_waitcnt vmcnt(NF+4)
// (drains exactly {A(t),B(t)}), barrier, compute, barrier. Never vmcnt(0)
// in steady loop. LDS holds A only: 24KB -> high block residency; reg cap 128.
// OMODE: 1 fp16 out TILED; 2 dual row-major fp16 out (O1=v, O2=v*scale[row]).
template<bool RELU, int OMODE, int BN_T, int NBN, int KK>
__global__ __launch_bounds__(256, 4) void gemm_kernel(
    const _Float16* __restrict__ A,
    const _Float16* __restrict__ B,
    const float* __restrict__ bias,
    void* __restrict__ O1, _Float16* __restrict__ O2, const float* __restrict__ scale,
    int M, int NNc, int xq, int xr)
{
    constexpr int NTK = KK / 32;           // k-steps
    constexpr int NF  = BN_T / 32;         // n-fragments per wave

    __shared__ _Float16 sA[3][128 * 32];

    const int tid  = threadIdx.x;
    const int lane = tid & 63;
    const int wv   = tid >> 6;
    const int wm   = wv >> 1;
    const int wn   = wv & 1;
    const int fr   = lane & 15;
    const int fc   = lane >> 4;

    // bijective XCD-chunk swizzle (m204)
    const int bid = blockIdx.x;
    const int xcd = bid & 7;
    const int i8  = bid >> 3;
    const int L   = ((xcd < xr) ? xcd * (xq + 1) : xr * (xq + 1) + (xcd - xr) * xq) + i8;
    const int mt  = L / NBN;
    const int bn  = L - mt * NBN;
    const int bm0 = mt * 128;
    const int bn0 = bn * BN_T;

    // per-lane offset within a 1KB staging block (chunk XOR-swizzled source)
    const int loff = (lane >> 2) * 32 + ((lane & 3) ^ ((lane >> 3) & 3)) * 8;

    f32x4 acc[4][NF] = {};
    h16x8 b0f[NF], b1f[NF];

    auto stageA = [&](int b, int t){
        const _Float16* as = A + ((size_t)mt * NTK + t) * 4096;
        gll16(as + (wv * 2)     * 512 + loff, sA[b] + (wv * 2)     * 512);
        gll16(as + (wv * 2 + 1) * 512 + loff, sA[b] + (wv * 2 + 1) * 512);
    };

    auto loadB = [&](h16x8 (&bf)[NF], int t){
        const _Float16* bs = B + ((size_t)bn * NTK + t) * 4096;
        #pragma unroll
        for (int nf = 0; nf < NF; nf++)
            bf[nf] = *(const h16x8*)(bs + (wn * (BN_T / 2) + nf * 16 + fr) * 32 + fc * 8);
    };

    auto compute = [&](h16x8 (&bf)[NF], int b3){
        h16x8 af[4];
        #pragma unroll
        for (int mf = 0; mf < 4; mf++){
            int r = wm * 64 + mf * 16 + fr;
            int c = (fc ^ ((r >> 1) & 3)) * 8;
            af[mf] = *(const h16x8*)&sA[b3][r * 32 + c];
        }
        __builtin_amdgcn_s_setprio(1);
        #pragma unroll
        for (int mf = 0; mf < 4; mf++)
            #pragma unroll
            for (int nf = 0; nf < NF; nf++)
                acc[mf][nf] = __builtin_amdgcn_mfma_f32_16x16x32_f16(af[mf], bf[nf], acc[mf][nf], 0, 0, 0);
        __builtin_amdgcn_s_setprio(0);
    };

    // prologue: B(0) first (oldest in FIFO), then A(0), A(1)
    loadB(b0f, 0);
    stageA(0, 0);
    stageA(1, 1);
    #pragma unroll
    for (int t = 0; t < NTK; t++){
        if (t + 1 < NTK){
            if ((t + 1) & 1) loadB(b1f, t + 1);
            else             loadB(b0f, t + 1);
        }
        if (t + 2 < NTK) stageA((t + 2) % 3, t + 2);
        if (t + 2 < NTK){
            if constexpr (NF == 4) asm volatile("s_waitcnt vmcnt(8)" ::: "memory");
            else                   asm volatile("s_waitcnt vmcnt(6)" ::: "memory");
        } else if (t + 1 < NTK){
            if constexpr (NF == 4) asm volatile("s_waitcnt vmcnt(6)" ::: "memory");
            else                   asm volatile("s_waitcnt vmcnt(4)" ::: "memory");
        } else {
            asm volatile("s_waitcnt vmcnt(0)" ::: "memory");
        }
        __builtin_amdgcn_s_barrier();       // sA[t%3] complete for all waves
        asm volatile("" ::: "memory");
        if (t & 1) compute(b1f, t % 3);
        else       compute(b0f, t % 3);
        asm volatile("" ::: "memory");
        __builtin_amdgcn_s_barrier();       // all reads of sA[t%3] retired
        asm volatile("" ::: "memory");
    }

    // ---- epilogue ----
    #pragma unroll
    for (int mf = 0; mf < 4; mf++){
        #pragma unroll
        for (int nf = 0; nf < NF; nf++){
            #pragma unroll
            for (int r = 0; r < 4; r++){
                int rg = bm0 + wm * 64 + mf * 16 + fc * 4 + r;
                int cg = bn0 + wn * (BN_T / 2) + nf * 16 + fr;
                if (rg < M){
                    float v = acc[mf][nf][r] + bias[cg];
                    if constexpr (RELU) v = fmaxf(v, 0.f);
                    if constexpr (OMODE == 1){
                        size_t o = ((size_t)mt * (NNc >> 5) + (cg >> 5)) * 4096
                                 + (size_t)(rg & 127) * 32 + (cg & 31);
                        ((_Float16*)O1)[o] = (_Float16)v;
                    } else {
                        ((_Float16*)O1)[(size_t)rg * NNc + cg] = (_Float16)v;
                        O2[(size_t)rg * NNc + cg] = (_Float16)(v * scale[rg]);
                    }
                }
            }
        }
    }
}

// ---------------- graph preprocessing ----------------
__global__ void degrees_kernel(const int* __restrict__ src, const int* __restrict__ dst,
                               int* __restrict__ dout, int* __restrict__ din){
    int e = blockIdx.x * blockDim.x + threadIdx.x;
    if (e < NE_EDGES){
        atomicAdd(&dout[src[e]], 1);
        atomicAdd(&din[dst[e]], 1);
    }
}

__global__ void norm_kernel(const int* __restrict__ dout, const int* __restrict__ din,
                            float* __restrict__ ns, float* __restrict__ nd, int n){
    int i = blockIdx.x * blockDim.x + threadIdx.x;
    if (i < n){
        ns[i] = rsqrtf((float)(dout[i] > 1 ? dout[i] : 1));
        nd[i] = rsqrtf((float)(din[i]  > 1 ? din[i]  : 1));
    }
}

__global__ __launch_bounds__(256) void scan1_kernel(const int* __restrict__ din,
                                                    int* __restrict__ part,
                                                    int* __restrict__ bsum, int n){
    __shared__ int s[256];
    int i = blockIdx.x * 256 + threadIdx.x;
    int v = (i < n) ? din[i] : 0;
    s[threadIdx.x] = v;
    __syncthreads();
    for (int off = 1; off < 256; off <<= 1){
        int t = (threadIdx.x >= off) ? s[threadIdx.x - off] : 0;
        __syncthreads();
        s[threadIdx.x] += t;
        __syncthreads();
    }
    if (i < n) part[i] = s[threadIdx.x];
    if (threadIdx.x == 255) bsum[blockIdx.x] = s[255];
}

__global__ __launch_bounds__(512) void scan2_kernel(int* __restrict__ bsum, int nb){
    __shared__ int s[512];
    int v = (threadIdx.x < nb) ? bsum[threadIdx.x] : 0;
    s[threadIdx.x] = v;
    __syncthreads();
    for (int off = 1; off < 512; off <<= 1){
        int t = (threadIdx.x >= off) ? s[threadIdx.x - off] : 0;
        __syncthreads();
        s[threadIdx.x] += t;
        __syncthreads();
    }
    if (threadIdx.x < nb) bsum[threadIdx.x] = s[threadIdx.x];
}

__global__ void scan3_kernel(const int* __restrict__ part, const int* __restrict__ din,
                             const int* __restrict__ bsum, int* __restrict__ offs,
                             int* __restrict__ cur, int n){
    int i = blockIdx.x * 256 + threadIdx.x;
    if (i < n){
        int base = (blockIdx.x > 0) ? bsum[blockIdx.x - 1] : 0;
        int excl = base + part[i] - din[i];
        offs[i] = excl;
        cur[i]  = excl;
    }
}

__global__ void fill_kernel(const int* __restrict__ src, const int* __restrict__ dst,
                            int* __restrict__ cur, int* __restrict__ csr){
    int e = blockIdx.x * blockDim.x + threadIdx.x;
    if (e < NE_EDGES){
        int d = dst[e];
        int pos = atomicAdd(&cur[d], 1);
        csr[pos] = src[e];
    }
}

// ---------------- APPNP propagation v3: 8 lanes per node ----------------
// hs = h * norm_src (fp16). Each 8-lane group owns one node; lane owns a 16B
// slice (8 channels). No cross-lane reduce, no divergent epilogue.
// h0h is fp16. Writes houts = out*ns (iters 0..8) or hout = out fp32 (final).
__global__ __launch_bounds__(256) void propagate_kernel(
    const _Float16* __restrict__ hs, const _Float16* __restrict__ h0h,
    float* __restrict__ hout, _Float16* __restrict__ houts,
    const int* __restrict__ offs, const int* __restrict__ din,
    const int* __restrict__ csr,
    const float* __restrict__ ns, const float* __restrict__ nd)
{
    int t    = blockIdx.x * 256 + threadIdx.x;
    int node = t >> 3;
    int gl   = t & 7;
    if (node >= NN_NODES) return;
    int start = offs[node];
    int deg   = din[node];
    float acc[8] = {};
    for (int j = 0; j < deg; j++){
        int s = csr[start + j];                       // 8 lanes same addr -> broadcast
        h16x8 v = *(const h16x8*)(hs + (size_t)s * D_C + gl * 8);
        #pragma unroll
        for (int i = 0; i < 8; i++) acc[i] += (float)v[i];
    }
    float ndv = 0.9f * nd[node];
    h16x8 h0v = *(const h16x8*)(h0h + (size_t)node * D_C + gl * 8);
    float out[8];
    #pragma unroll
    for (int i = 0; i < 8; i++) out[i] = acc[i] * ndv + 0.1f * (float)h0v[i];
    if (houts){
        float nsv = ns[node];
        h16x8 o;
        #pragma unroll
        for (int i = 0; i < 8; i++) o[i] = (_Float16)(out[i] * nsv);
        *(h16x8*)(houts + (size_t)node * D_C + gl * 8) = o;
    }
    if (hout){
        f32x4 oa, ob;
        #pragma unroll
        for (int i = 0; i < 4; i++){ oa[i] = out[i]; ob[i] = out[i + 4]; }
        *(f32x4*)(hout + (size_t)node * D_C + gl * 8)     = oa;
        *(f32x4*)(hout + (size_t)node * D_C + gl * 8 + 4) = ob;
    }
}

// ---------------- launch ----------------
extern "C" void kernel_launch(void* const* d_in, const int* in_sizes, int n_in,
                              void* d_out, int out_size, void* d_ws, size_t ws_size,
                              hipStream_t stream)
{
    const float* features = (const float*)d_in[0];
    const int*   edge     = (const int*)d_in[1];
    const float* W0 = (const float*)d_in[2];
    const float* b0 = (const float*)d_in[3];
    const float* W1 = (const float*)d_in[4];
    const float* b1 = (const float*)d_in[5];
    const float* W2 = (const float*)d_in[6];
    const float* b2 = (const float*)d_in[7];
    const int* src = edge;
    const int* dst = edge + NE_EDGES;

    char* p = (char*)d_ws;
    auto alloc = [&](size_t bytes) -> char* {
        char* r = p;
        p += (bytes + 255) & ~(size_t)255;
        return r;
    };

    const int MT = (NN_NODES + 127) / 128;              // 782 m-tiles
    const size_t FEAT_T = (size_t)MT * 16 * 4096 * 2;   // tiled fp16, K=512
    const size_t HBUFH  = (size_t)NN_NODES * D_C * 2;   // 12.8 MB fp16

    _Float16* w0f = (_Float16*)alloc((size_t)4 * 16 * 4096 * 2);  // 512 rows
    _Float16* w1f = (_Float16*)alloc((size_t)2 * 16 * 4096 * 2);  // 256 rows
    _Float16* w2f = (_Float16*)alloc((size_t)1 * 8  * 4096 * 2);  // 64 rows
    char* R1 = alloc(FEAT_T);          // fhf (tiled); later act2 (tiled)
    char* R2 = alloc(FEAT_T);          // act1 (tiled); later h0h + h0s + hAs + hBs
    int*   deg_out = (int*)alloc((size_t)NN_NODES * 4);
    int*   deg_in  = (int*)alloc((size_t)NN_NODES * 4);
    float* nsrc    = (float*)alloc((size_t)NN_NODES * 4);
    float* ndst    = (float*)alloc((size_t)NN_NODES * 4);
    int*   part    = (int*)alloc((size_t)NN_NODES * 4);
    int*   bsum    = (int*)alloc(2048);
    int*   offs    = (int*)alloc((size_t)NN_NODES * 4);
    int*   cur     = (int*)alloc((size_t)NN_NODES * 4);
    int*   csr     = (int*)alloc((size_t)NE_EDGES * 4);
    if ((size_t)(p - (char*)d_ws) > ws_size) return;

    _Float16* fhf  = (_Float16*)R1;          // dead after GEMM1
    _Float16* act2 = (_Float16*)R1;          // written by GEMM2 (tiled)
    _Float16* act1 = (_Float16*)R2;          // dead after GEMM2
    _Float16* h0h  = (_Float16*)R2;          // written by GEMM3 (row-major fp16)
    _Float16* h0s  = (_Float16*)(R2 + HBUFH);
    _Float16* hAs  = (_Float16*)(R2 + 2 * HBUFH);
    _Float16* hBs  = (_Float16*)(R2 + 3 * HBUFH);

    // --- graph preprocessing ---
    hipMemsetAsync(deg_out, 0, (size_t)NN_NODES * 4, stream);
    hipMemsetAsync(deg_in,  0, (size_t)NN_NODES * 4, stream);
    degrees_kernel<<<(NE_EDGES + 255) / 256, 256, 0, stream>>>(src, dst, deg_out, deg_in);
    norm_kernel<<<(NN_NODES + 255) / 256, 256, 0, stream>>>(deg_out, deg_in, nsrc, ndst, NN_NODES);
    int nb = (NN_NODES + 255) / 256;
    scan1_kernel<<<nb, 256, 0, stream>>>(deg_in, part, bsum, NN_NODES);
    scan2_kernel<<<1, 512, 0, stream>>>(bsum, nb);
    scan3_kernel<<<nb, 256, 0, stream>>>(part, deg_in, bsum, offs, cur, NN_NODES);
    fill_kernel<<<(NE_EDGES + 255) / 256, 256, 0, stream>>>(src, dst, cur, csr);

    // --- conversions (fp32 row-major -> fp16 tiled) ---
    tof16_tiled_kernel<<<(NN_NODES * D_IN / 8 + 255) / 256, 256, 0, stream>>>(
        features, fhf, NN_NODES, D_IN);
    tof16_tiled_kernel<<<(D_H0 * D_IN / 8 + 255) / 256, 256, 0, stream>>>(W0, w0f, D_H0, D_IN);
    tof16_tiled_kernel<<<(D_H1 * D_H0 / 8 + 255) / 256, 256, 0, stream>>>(W1, w1f, D_H1, D_H0);
    tof16_tiled_kernel<<<(D_C * D_H1 / 8 + 255) / 256, 256, 0, stream>>>(W2, w2f, D_C, D_H1);

    // --- MLP ---
    {   // L0: [100k,512] x [512,512]^T, relu, tiled fp16 out
        int nwg = MT * 4;
        gemm_kernel<true, 1, 128, 4, 512><<<nwg, 256, 0, stream>>>(
            fhf, w0f, b0, act1, nullptr, nullptr, NN_NODES, D_H0, nwg / 8, nwg % 8);
    }
    {   // L1: [100k,512] x [256,512]^T, relu, tiled fp16 out
        int nwg = MT * 2;
        gemm_kernel<true, 1, 128, 2, 512><<<nwg, 256, 0, stream>>>(
            act1, w1f, b1, act2, nullptr, nullptr, NN_NODES, D_H1, nwg / 8, nwg % 8);
    }
    {   // L2: [100k,256] x [64,256]^T, dual row-major fp16 out (h0h, h0s=h0*ns)
        int nwg = MT;
        gemm_kernel<false, 2, 64, 1, 256><<<nwg, 256, 0, stream>>>(
            act2, w2f, b2, h0h, h0s, nsrc, NN_NODES, D_C, nwg / 8, nwg % 8);
    }

    // --- APPNP: 10 propagation steps (8 lanes per node) ---
    const _Float16* curs = h0s;
    _Float16* bufss[2] = { hAs, hBs };
    int pb = (NN_NODES * 8 + 255) / 256;   // 3125 blocks
    for (int it = 0; it < 10; it++){
        float*    out  = (it == 9) ? (float*)d_out : nullptr;
        _Float16* outs = (it == 9) ? nullptr       : bufss[it & 1];
        propagate_kernel<<<pb, 256, 0, stream>>>(curs, h0h, out, outs, offs, deg_in, csr, nsrc, ndst);
        curs = outs;
    }
}

// Round 11
// 666.724 us; speedup vs baseline: 1.6053x; 1.1545x over previous
//
#include <hip/hip_runtime.h>
#include <hip/hip_bf16.h>

#define NN_NODES 100000
#define NE_EDGES 1000000
#define D_IN 512
#define D_H0 512
#define D_H1 256
#define D_C  64

using f32x4  = __attribute__((ext_vector_type(4))) float;
using h16x8  = __attribute__((ext_vector_type(8))) _Float16;

// async global->LDS, 16B/lane; LDS dest = wave-uniform base + lane*16
static __device__ __forceinline__ void gll16(const _Float16* g, _Float16* l){
    __builtin_amdgcn_global_load_lds(
        (const __attribute__((address_space(1))) unsigned int*)g,
        (__attribute__((address_space(3))) unsigned int*)l, 16, 0, 0);
}

// ---------------- fp32 row-major -> fp16 TILED [(R/128)][(K/32)][128x32] ----------------
__global__ __launch_bounds__(256) void tof16_tiled_kernel(
    const float* __restrict__ w, _Float16* __restrict__ o, int R, int K)
{
    int i = blockIdx.x * 256 + threadIdx.x;      // 8 elems along a row
    int n8 = R * (K >> 3);
    if (i >= n8) return;
    int kd = K >> 3;
    int r  = i / kd;
    int c0 = (i - r * kd) * 8;
    const f32x4 a = *(const f32x4*)(w + (size_t)r * K + c0);
    const f32x4 b = *(const f32x4*)(w + (size_t)r * K + c0 + 4);
    h16x8 h;
    #pragma unroll
    for (int j = 0; j < 4; j++){
        h[j]   = (_Float16)a[j];
        h[j+4] = (_Float16)b[j];
    }
    size_t off = ((size_t)(r >> 7) * (K >> 5) + (c0 >> 5)) * 4096
               + (size_t)(r & 127) * 32 + (c0 & 31);
    *(h16x8*)(o + off) = h;
}

// ---------------- GEMM: C[M,NNc] = act( A[M,K] * B[NNc,K]^T + bias ) ----------------
// A fp16 tiled, staged to LDS via gll (3 buffers, depth-2 counted vmcnt).
// B fp16 tiled, consumed DIRECTLY global->reg (L2-resident weights), double-
// buffered in regs; tiled layout -> contiguous 1KB fragment loads per wave.
// Issue order per k-step: loadB(t+1), stageA(t+2), s_waitcnt vmcnt(NF+4)
// (drains exactly {A(t),B(t)}), barrier, compute, barrier. Never vmcnt(0)
// in steady loop.
// __launch_bounds__(256,3): 170-reg budget -- acc(64 AGPR) + af(16) +
// b0f/b1f(32) + addressing fits WITHOUT spills (the (256,4)=128-reg cap
// spilled the B buffers to scratch: +81MB HBM round-trip, the r10 regression).
// OMODE: 1 fp16 out TILED; 2 dual row-major fp16 out (O1=v, O2=v*scale[row]).
template<bool RELU, int OMODE, int BN_T, int NBN, int KK>
__global__ __launch_bounds__(256, 3) void gemm_kernel(
    const _Float16* __restrict__ A,
    const _Float16* __restrict__ B,
    const float* __restrict__ bias,
    void* __restrict__ O1, _Float16* __restrict__ O2, const float* __restrict__ scale,
    int M, int NNc, int xq, int xr)
{
    constexpr int NTK = KK / 32;           // k-steps
    constexpr int NF  = BN_T / 32;         // n-fragments per wave

    __shared__ _Float16 sA[3][128 * 32];

    const int tid  = threadIdx.x;
    const int lane = tid & 63;
    const int wv   = tid >> 6;
    const int wm   = wv >> 1;
    const int wn   = wv & 1;
    const int fr   = lane & 15;
    const int fc   = lane >> 4;

    // bijective XCD-chunk swizzle (m204)
    const int bid = blockIdx.x;
    const int xcd = bid & 7;
    const int i8  = bid >> 3;
    const int L   = ((xcd < xr) ? xcd * (xq + 1) : xr * (xq + 1) + (xcd - xr) * xq) + i8;
    const int mt  = L / NBN;
    const int bn  = L - mt * NBN;
    const int bm0 = mt * 128;
    const int bn0 = bn * BN_T;

    // per-lane offset within a 1KB staging block (chunk XOR-swizzled source)
    const int loff = (lane >> 2) * 32 + ((lane & 3) ^ ((lane >> 3) & 3)) * 8;

    f32x4 acc[4][NF] = {};
    h16x8 b0f[NF], b1f[NF];

    auto stageA = [&](int b, int t){
        const _Float16* as = A + ((size_t)mt * NTK + t) * 4096;
        gll16(as + (wv * 2)     * 512 + loff, sA[b] + (wv * 2)     * 512);
        gll16(as + (wv * 2 + 1) * 512 + loff, sA[b] + (wv * 2 + 1) * 512);
    };

    auto loadB = [&](h16x8 (&bf)[NF], int t){
        const _Float16* bs = B + ((size_t)bn * NTK + t) * 4096;
        #pragma unroll
        for (int nf = 0; nf < NF; nf++)
            bf[nf] = *(const h16x8*)(bs + (wn * (BN_T / 2) + nf * 16 + fr) * 32 + fc * 8);
    };

    auto compute = [&](h16x8 (&bf)[NF], int b3){
        h16x8 af[4];
        #pragma unroll
        for (int mf = 0; mf < 4; mf++){
            int r = wm * 64 + mf * 16 + fr;
            int c = (fc ^ ((r >> 1) & 3)) * 8;
            af[mf] = *(const h16x8*)&sA[b3][r * 32 + c];
        }
        __builtin_amdgcn_s_setprio(1);
        #pragma unroll
        for (int mf = 0; mf < 4; mf++)
            #pragma unroll
            for (int nf = 0; nf < NF; nf++)
                acc[mf][nf] = __builtin_amdgcn_mfma_f32_16x16x32_f16(af[mf], bf[nf], acc[mf][nf], 0, 0, 0);
        __builtin_amdgcn_s_setprio(0);
    };

    // prologue: B(0) first (oldest in FIFO), then A(0), A(1)
    loadB(b0f, 0);
    stageA(0, 0);
    stageA(1, 1);
    #pragma unroll
    for (int t = 0; t < NTK; t++){
        if (t + 1 < NTK){
            if ((t + 1) & 1) loadB(b1f, t + 1);
            else             loadB(b0f, t + 1);
        }
        if (t + 2 < NTK) stageA((t + 2) % 3, t + 2);
        if (t + 2 < NTK){
            // in flight: B(t+1)=NF, A(t+1)=2, A(t+2)=2 -> keep NF+4
            if constexpr (NF == 4) asm volatile("s_waitcnt vmcnt(8)" ::: "memory");
            else                   asm volatile("s_waitcnt vmcnt(6)" ::: "memory");
        } else if (t + 1 < NTK){
            if constexpr (NF == 4) asm volatile("s_waitcnt vmcnt(6)" ::: "memory");
            else                   asm volatile("s_waitcnt vmcnt(4)" ::: "memory");
        } else {
            asm volatile("s_waitcnt vmcnt(0)" ::: "memory");
        }
        __builtin_amdgcn_s_barrier();       // sA[t%3] complete for all waves
        asm volatile("" ::: "memory");
        if (t & 1) compute(b1f, t % 3);
        else       compute(b0f, t % 3);
        asm volatile("" ::: "memory");
        __builtin_amdgcn_s_barrier();       // all reads of sA[t%3] retired
        asm volatile("" ::: "memory");
    }

    // ---- epilogue ----
    #pragma unroll
    for (int mf = 0; mf < 4; mf++){
        #pragma unroll
        for (int nf = 0; nf < NF; nf++){
            #pragma unroll
            for (int r = 0; r < 4; r++){
                int rg = bm0 + wm * 64 + mf * 16 + fc * 4 + r;
                int cg = bn0 + wn * (BN_T / 2) + nf * 16 + fr;
                if (rg < M){
                    float v = acc[mf][nf][r] + bias[cg];
                    if constexpr (RELU) v = fmaxf(v, 0.f);
                    if constexpr (OMODE == 1){
                        size_t o = ((size_t)mt * (NNc >> 5) + (cg >> 5)) * 4096
                                 + (size_t)(rg & 127) * 32 + (cg & 31);
                        ((_Float16*)O1)[o] = (_Float16)v;
                    } else {
                        ((_Float16*)O1)[(size_t)rg * NNc + cg] = (_Float16)v;
                        O2[(size_t)rg * NNc + cg] = (_Float16)(v * scale[rg]);
                    }
                }
            }
        }
    }
}

// ---------------- graph preprocessing ----------------
__global__ void degrees_kernel(const int* __restrict__ src, const int* __restrict__ dst,
                               int* __restrict__ dout, int* __restrict__ din){
    int e = blockIdx.x * blockDim.x + threadIdx.x;
    if (e < NE_EDGES){
        atomicAdd(&dout[src[e]], 1);
        atomicAdd(&din[dst[e]], 1);
    }
}

__global__ void norm_kernel(const int* __restrict__ dout, const int* __restrict__ din,
                            float* __restrict__ ns, float* __restrict__ nd, int n){
    int i = blockIdx.x * blockDim.x + threadIdx.x;
    if (i < n){
        ns[i] = rsqrtf((float)(dout[i] > 1 ? dout[i] : 1));
        nd[i] = rsqrtf((float)(din[i]  > 1 ? din[i]  : 1));
    }
}

__global__ __launch_bounds__(256) void scan1_kernel(const int* __restrict__ din,
                                                    int* __restrict__ part,
                                                    int* __restrict__ bsum, int n){
    __shared__ int s[256];
    int i = blockIdx.x * 256 + threadIdx.x;
    int v = (i < n) ? din[i] : 0;
    s[threadIdx.x] = v;
    __syncthreads();
    for (int off = 1; off < 256; off <<= 1){
        int t = (threadIdx.x >= off) ? s[threadIdx.x - off] : 0;
        __syncthreads();
        s[threadIdx.x] += t;
        __syncthreads();
    }
    if (i < n) part[i] = s[threadIdx.x];
    if (threadIdx.x == 255) bsum[blockIdx.x] = s[255];
}

__global__ __launch_bounds__(512) void scan2_kernel(int* __restrict__ bsum, int nb){
    __shared__ int s[512];
    int v = (threadIdx.x < nb) ? bsum[threadIdx.x] : 0;
    s[threadIdx.x] = v;
    __syncthreads();
    for (int off = 1; off < 512; off <<= 1){
        int t = (threadIdx.x >= off) ? s[threadIdx.x - off] : 0;
        __syncthreads();
        s[threadIdx.x] += t;
        __syncthreads();
    }
    if (threadIdx.x < nb) bsum[threadIdx.x] = s[threadIdx.x];
}

__global__ void scan3_kernel(const int* __restrict__ part, const int* __restrict__ din,
                             const int* __restrict__ bsum, int* __restrict__ offs,
                             int* __restrict__ cur, int n){
    int i = blockIdx.x * 256 + threadIdx.x;
    if (i < n){
        int base = (blockIdx.x > 0) ? bsum[blockIdx.x - 1] : 0;
        int excl = base + part[i] - din[i];
        offs[i] = excl;
        cur[i]  = excl;
    }
}

__global__ void fill_kernel(const int* __restrict__ src, const int* __restrict__ dst,
                            int* __restrict__ cur, int* __restrict__ csr){
    int e = blockIdx.x * blockDim.x + threadIdx.x;
    if (e < NE_EDGES){
        int d = dst[e];
        int pos = atomicAdd(&cur[d], 1);
        csr[pos] = src[e];
    }
}

// ---------------- APPNP propagation v3.1: 8 lanes per node, 2-way unrolled ----------------
// hs = h * norm_src (fp16). Each 8-lane group owns one node; lane owns 8
// channels (16B). Gather loop unrolled x2: two independent row loads in
// flight per group (halves the dependent-load latency chain).
__global__ __launch_bounds__(256) void propagate_kernel(
    const _Float16* __restrict__ hs, const _Float16* __restrict__ h0h,
    float* __restrict__ hout, _Float16* __restrict__ houts,
    const int* __restrict__ offs, const int* __restrict__ din,
    const int* __restrict__ csr,
    const float* __restrict__ ns, const float* __restrict__ nd)
{
    int t    = blockIdx.x * 256 + threadIdx.x;
    int node = t >> 3;
    int gl   = t & 7;
    if (node >= NN_NODES) return;
    int start = offs[node];
    int deg   = din[node];
    float acc[8] = {};
    int j = 0;
    for (; j + 2 <= deg; j += 2){
        int s0 = csr[start + j];
        int s1 = csr[start + j + 1];
        h16x8 v0 = *(const h16x8*)(hs + (size_t)s0 * D_C + gl * 8);
        h16x8 v1 = *(const h16x8*)(hs + (size_t)s1 * D_C + gl * 8);
        #pragma unroll
        for (int i = 0; i < 8; i++) acc[i] += (float)v0[i] + (float)v1[i];
    }
    if (j < deg){
        int s0 = csr[start + j];
        h16x8 v0 = *(const h16x8*)(hs + (size_t)s0 * D_C + gl * 8);
        #pragma unroll
        for (int i = 0; i < 8; i++) acc[i] += (float)v0[i];
    }
    float ndv = 0.9f * nd[node];
    h16x8 h0v = *(const h16x8*)(h0h + (size_t)node * D_C + gl * 8);
    float out[8];
    #pragma unroll
    for (int i = 0; i < 8; i++) out[i] = acc[i] * ndv + 0.1f * (float)h0v[i];
    if (houts){
        float nsv = ns[node];
        h16x8 o;
        #pragma unroll
        for (int i = 0; i < 8; i++) o[i] = (_Float16)(out[i] * nsv);
        *(h16x8*)(houts + (size_t)node * D_C + gl * 8) = o;
    }
    if (hout){
        f32x4 oa, ob;
        #pragma unroll
        for (int i = 0; i < 4; i++){ oa[i] = out[i]; ob[i] = out[i + 4]; }
        *(f32x4*)(hout + (size_t)node * D_C + gl * 8)     = oa;
        *(f32x4*)(hout + (size_t)node * D_C + gl * 8 + 4) = ob;
    }
}

// ---------------- launch ----------------
extern "C" void kernel_launch(void* const* d_in, const int* in_sizes, int n_in,
                              void* d_out, int out_size, void* d_ws, size_t ws_size,
                              hipStream_t stream)
{
    const float* features = (const float*)d_in[0];
    const int*   edge     = (const int*)d_in[1];
    const float* W0 = (const float*)d_in[2];
    const float* b0 = (const float*)d_in[3];
    const float* W1 = (const float*)d_in[4];
    const float* b1 = (const float*)d_in[5];
    const float* W2 = (const float*)d_in[6];
    const float* b2 = (const float*)d_in[7];
    const int* src = edge;
    const int* dst = edge + NE_EDGES;

    char* p = (char*)d_ws;
    auto alloc = [&](size_t bytes) -> char* {
        char* r = p;
        p += (bytes + 255) & ~(size_t)255;
        return r;
    };

    const int MT = (NN_NODES + 127) / 128;              // 782 m-tiles
    const size_t FEAT_T = (size_t)MT * 16 * 4096 * 2;   // tiled fp16, K=512
    const size_t HBUFH  = (size_t)NN_NODES * D_C * 2;   // 12.8 MB fp16

    _Float16* w0f = (_Float16*)alloc((size_t)4 * 16 * 4096 * 2);  // 512 rows
    _Float16* w1f = (_Float16*)alloc((size_t)2 * 16 * 4096 * 2);  // 256 rows
    _Float16* w2f = (_Float16*)alloc((size_t)1 * 8  * 4096 * 2);  // 64 rows
    char* R1 = alloc(FEAT_T);          // fhf (tiled); later act2 (tiled)
    char* R2 = alloc(FEAT_T);          // act1 (tiled); later h0h + h0s + hAs + hBs
    int*   deg_out = (int*)alloc((size_t)NN_NODES * 4);
    int*   deg_in  = (int*)alloc((size_t)NN_NODES * 4);
    float* nsrc    = (float*)alloc((size_t)NN_NODES * 4);
    float* ndst    = (float*)alloc((size_t)NN_NODES * 4);
    int*   part    = (int*)alloc((size_t)NN_NODES * 4);
    int*   bsum    = (int*)alloc(2048);
    int*   offs    = (int*)alloc((size_t)NN_NODES * 4);
    int*   cur     = (int*)alloc((size_t)NN_NODES * 4);
    int*   csr     = (int*)alloc((size_t)NE_EDGES * 4);
    if ((size_t)(p - (char*)d_ws) > ws_size) return;

    _Float16* fhf  = (_Float16*)R1;          // dead after GEMM1
    _Float16* act2 = (_Float16*)R1;          // written by GEMM2 (tiled)
    _Float16* act1 = (_Float16*)R2;          // dead after GEMM2
    _Float16* h0h  = (_Float16*)R2;          // written by GEMM3 (row-major fp16)
    _Float16* h0s  = (_Float16*)(R2 + HBUFH);
    _Float16* hAs  = (_Float16*)(R2 + 2 * HBUFH);
    _Float16* hBs  = (_Float16*)(R2 + 3 * HBUFH);

    // --- graph preprocessing ---
    hipMemsetAsync(deg_out, 0, (size_t)NN_NODES * 4, stream);
    hipMemsetAsync(deg_in,  0, (size_t)NN_NODES * 4, stream);
    degrees_kernel<<<(NE_EDGES + 255) / 256, 256, 0, stream>>>(src, dst, deg_out, deg_in);
    norm_kernel<<<(NN_NODES + 255) / 256, 256, 0, stream>>>(deg_out, deg_in, nsrc, ndst, NN_NODES);
    int nb = (NN_NODES + 255) / 256;
    scan1_kernel<<<nb, 256, 0, stream>>>(deg_in, part, bsum, NN_NODES);
    scan2_kernel<<<1, 512, 0, stream>>>(bsum, nb);
    scan3_kernel<<<nb, 256, 0, stream>>>(part, deg_in, bsum, offs, cur, NN_NODES);
    fill_kernel<<<(NE_EDGES + 255) / 256, 256, 0, stream>>>(src, dst, cur, csr);

    // --- conversions (fp32 row-major -> fp16 tiled) ---
    tof16_tiled_kernel<<<(NN_NODES * D_IN / 8 + 255) / 256, 256, 0, stream>>>(
        features, fhf, NN_NODES, D_IN);
    tof16_tiled_kernel<<<(D_H0 * D_IN / 8 + 255) / 256, 256, 0, stream>>>(W0, w0f, D_H0, D_IN);
    tof16_tiled_kernel<<<(D_H1 * D_H0 / 8 + 255) / 256, 256, 0, stream>>>(W1, w1f, D_H1, D_H0);
    tof16_tiled_kernel<<<(D_C * D_H1 / 8 + 255) / 256, 256, 0, stream>>>(W2, w2f, D_C, D_H1);

    // --- MLP ---
    {   // L0: [100k,512] x [512,512]^T, relu, tiled fp16 out
        int nwg = MT * 4;
        gemm_kernel<true, 1, 128, 4, 512><<<nwg, 256, 0, stream>>>(
            fhf, w0f, b0, act1, nullptr, nullptr, NN_NODES, D_H0, nwg / 8, nwg % 8);
    }
    {   // L1: [100k,512] x [256,512]^T, relu, tiled fp16 out
        int nwg = MT * 2;
        gemm_kernel<true, 1, 128, 2, 512><<<nwg, 256, 0, stream>>>(
            act1, w1f, b1, act2, nullptr, nullptr, NN_NODES, D_H1, nwg / 8, nwg % 8);
    }
    {   // L2: [100k,256] x [64,256]^T, dual row-major fp16 out (h0h, h0s=h0*ns)
        int nwg = MT;
        gemm_kernel<false, 2, 64, 1, 256><<<nwg, 256, 0, stream>>>(
            act2, w2f, b2, h0h, h0s, nsrc, NN_NODES, D_C, nwg / 8, nwg % 8);
    }

    // --- APPNP: 10 propagation steps (8 lanes per node) ---
    const _Float16* curs = h0s;
    _Float16* bufss[2] = { hAs, hBs };
    int pb = (NN_NODES * 8 + 255) / 256;   // 3125 blocks
    for (int it = 0; it < 10; it++){
        float*    out  = (it == 9) ? (float*)d_out : nullptr;
        _Float16* outs = (it == 9) ? nullptr       : bufss[it & 1];
        propagate_kernel<<<pb, 256, 0, stream>>>(curs, h0h, out, outs, offs, deg_in, csr, nsrc, ndst);
        curs = outs;
    }
}

// Round 12
// 635.923 us; speedup vs baseline: 1.6830x; 1.0484x over previous
//
#include <hip/hip_runtime.h>
#include <hip/hip_bf16.h>

#define NN_NODES 100000
#define NE_EDGES 1000000
#define D_IN 512
#define D_H0 512
#define D_H1 256
#define D_C  64

using f32x4  = __attribute__((ext_vector_type(4))) float;
using h16x8  = __attribute__((ext_vector_type(8))) _Float16;

// async global->LDS, 16B/lane; LDS dest = wave-uniform base + lane*16
static __device__ __forceinline__ void gll16(const _Float16* g, _Float16* l){
    __builtin_amdgcn_global_load_lds(
        (const __attribute__((address_space(1))) unsigned int*)g,
        (__attribute__((address_space(3))) unsigned int*)l, 16, 0, 0);
}

// ---------------- fp32 row-major -> fp16 TILED [(R/128)][(K/32)][128x32] ----------------
__global__ __launch_bounds__(256) void tof16_tiled_kernel(
    const float* __restrict__ w, _Float16* __restrict__ o, int R, int K)
{
    int i = blockIdx.x * 256 + threadIdx.x;      // 8 elems along a row
    int n8 = R * (K >> 3);
    if (i >= n8) return;
    int kd = K >> 3;
    int r  = i / kd;
    int c0 = (i - r * kd) * 8;
    const f32x4 a = *(const f32x4*)(w + (size_t)r * K + c0);
    const f32x4 b = *(const f32x4*)(w + (size_t)r * K + c0 + 4);
    h16x8 h;
    #pragma unroll
    for (int j = 0; j < 4; j++){
        h[j]   = (_Float16)a[j];
        h[j+4] = (_Float16)b[j];
    }
    size_t off = ((size_t)(r >> 7) * (K >> 5) + (c0 >> 5)) * 4096
               + (size_t)(r & 127) * 32 + (c0 & 31);
    *(h16x8*)(o + off) = h;
}

// ---------------- GEMM: C[M,NNc] = act( A[M,K] * B[NNc,K]^T + bias ) ----------------
// Round-9 proven structure (empirical best: 2-buffer LDS, A+B staged via gll,
// ONE __syncthreads per k-step), narrowed to BN_T=64 so the whole wave state
// (acc 32 + af 16 + bf 8 + addressing) fits under the 128-reg occupancy
// bucket -> genuine 4 waves/SIMD. LDS 24KB -> 4 blocks/CU (reg-limited).
// Tiled operands: slab(rowblk, t) = [128][32] contiguous 8KB; staging loads
// are contiguous 1KB per gll. XOR chunk-swizzle both-sides (0 conflicts).
// OMODE: 1 fp16 out TILED; 2 dual row-major fp16 out (O1=v, O2=v*scale[row]).
template<bool RELU, int OMODE, int BN_T, int NBN, int KK>
__global__ __launch_bounds__(256, 4) void gemm_kernel(
    const _Float16* __restrict__ A,
    const _Float16* __restrict__ B,
    const float* __restrict__ bias,
    void* __restrict__ O1, _Float16* __restrict__ O2, const float* __restrict__ scale,
    int M, int NNc, int xq, int xr)
{
    constexpr int NTK  = KK / 32;          // k-steps
    constexpr int NF   = BN_T / 32;        // n-fragments per wave (2 for BN_T=64)
    constexpr int BBLK = BN_T / 16;        // 16-row gll blocks per B tile (4)
    constexpr int TOT  = 8 + BBLK;         // gll ops per k-step (12)
    constexpr int LPW  = TOT / 4;          // gll ops per wave per stage (3)

    __shared__ _Float16 sA[2][128 * 32];
    __shared__ _Float16 sB[2][BN_T * 32];

    const int tid  = threadIdx.x;
    const int lane = tid & 63;
    const int wv   = tid >> 6;
    const int wm   = wv >> 1;
    const int wn   = wv & 1;
    const int fr   = lane & 15;
    const int fc   = lane >> 4;

    // bijective XCD-chunk swizzle (m204)
    const int bid = blockIdx.x;
    const int xcd = bid & 7;
    const int i8  = bid >> 3;
    const int L   = ((xcd < xr) ? xcd * (xq + 1) : xr * (xq + 1) + (xcd - xr) * xq) + i8;
    const int mt  = L / NBN;
    const int bn  = L - mt * NBN;
    const int bm0 = mt * 128;
    const int bn0 = bn * BN_T;

    // B rows live in 128-row slabs: locate tile within its slab
    const int bslab = bn0 >> 7;
    const int binsl = bn0 & 127;

    // per-lane offset within a 1KB staging block (chunk XOR-swizzled source)
    const int loff = (lane >> 2) * 32 + ((lane & 3) ^ ((lane >> 3) & 3)) * 8;

    f32x4 acc[4][NF] = {};

    auto stage = [&](int b, int t){
        const _Float16* as = A + ((size_t)mt * NTK + t) * 4096;
        const _Float16* bs = B + ((size_t)bslab * NTK + t) * 4096 + binsl * 32;
        #pragma unroll
        for (int u = 0; u < LPW; u++){
            int idx = u * 4 + wv;
            if (idx < 8) gll16(as + idx * 512 + loff, sA[b] + idx * 512);
            else         gll16(bs + (idx - 8) * 512 + loff, sB[b] + (idx - 8) * 512);
        }
    };

    auto compute = [&](int b){
        h16x8 bf[NF];
        #pragma unroll
        for (int nf = 0; nf < NF; nf++){
            int r = wn * (BN_T / 2) + nf * 16 + fr;
            int c = (fc ^ ((r >> 1) & 3)) * 8;
            bf[nf] = *(const h16x8*)&sB[b][r * 32 + c];
        }
        h16x8 af[4];
        #pragma unroll
        for (int mf = 0; mf < 4; mf++){
            int r = wm * 64 + mf * 16 + fr;
            int c = (fc ^ ((r >> 1) & 3)) * 8;
            af[mf] = *(const h16x8*)&sA[b][r * 32 + c];
        }
        __builtin_amdgcn_s_setprio(1);
        #pragma unroll
        for (int mf = 0; mf < 4; mf++)
            #pragma unroll
            for (int nf = 0; nf < NF; nf++)
                acc[mf][nf] = __builtin_amdgcn_mfma_f32_16x16x32_f16(af[mf], bf[nf], acc[mf][nf], 0, 0, 0);
        __builtin_amdgcn_s_setprio(0);
    };

    stage(0, 0);
    __syncthreads();
    int cur = 0;
    for (int t = 0; t < NTK; t++){
        if (t + 1 < NTK) stage(cur ^ 1, t + 1);
        compute(cur);
        __syncthreads();
        cur ^= 1;
    }

    // ---- epilogue ----
    #pragma unroll
    for (int mf = 0; mf < 4; mf++){
        #pragma unroll
        for (int nf = 0; nf < NF; nf++){
            #pragma unroll
            for (int r = 0; r < 4; r++){
                int rg = bm0 + wm * 64 + mf * 16 + fc * 4 + r;
                int cg = bn0 + wn * (BN_T / 2) + nf * 16 + fr;
                if (rg < M){
                    float v = acc[mf][nf][r] + bias[cg];
                    if constexpr (RELU) v = fmaxf(v, 0.f);
                    if constexpr (OMODE == 1){
                        size_t o = ((size_t)mt * (NNc >> 5) + (cg >> 5)) * 4096
                                 + (size_t)(rg & 127) * 32 + (cg & 31);
                        ((_Float16*)O1)[o] = (_Float16)v;
                    } else {
                        ((_Float16*)O1)[(size_t)rg * NNc + cg] = (_Float16)v;
                        O2[(size_t)rg * NNc + cg] = (_Float16)(v * scale[rg]);
                    }
                }
            }
        }
    }
}

// ---------------- graph preprocessing ----------------
__global__ void degrees_kernel(const int* __restrict__ src, const int* __restrict__ dst,
                               int* __restrict__ dout, int* __restrict__ din){
    int e = blockIdx.x * blockDim.x + threadIdx.x;
    if (e < NE_EDGES){
        atomicAdd(&dout[src[e]], 1);
        atomicAdd(&din[dst[e]], 1);
    }
}

__global__ void norm_kernel(const int* __restrict__ dout, const int* __restrict__ din,
                            float* __restrict__ ns, float* __restrict__ nd, int n){
    int i = blockIdx.x * blockDim.x + threadIdx.x;
    if (i < n){
        ns[i] = rsqrtf((float)(dout[i] > 1 ? dout[i] : 1));
        nd[i] = rsqrtf((float)(din[i]  > 1 ? din[i]  : 1));
    }
}

__global__ __launch_bounds__(256) void scan1_kernel(const int* __restrict__ din,
                                                    int* __restrict__ part,
                                                    int* __restrict__ bsum, int n){
    __shared__ int s[256];
    int i = blockIdx.x * 256 + threadIdx.x;
    int v = (i < n) ? din[i] : 0;
    s[threadIdx.x] = v;
    __syncthreads();
    for (int off = 1; off < 256; off <<= 1){
        int t = (threadIdx.x >= off) ? s[threadIdx.x - off] : 0;
        __syncthreads();
        s[threadIdx.x] += t;
        __syncthreads();
    }
    if (i < n) part[i] = s[threadIdx.x];
    if (threadIdx.x == 255) bsum[blockIdx.x] = s[255];
}

__global__ __launch_bounds__(512) void scan2_kernel(int* __restrict__ bsum, int nb){
    __shared__ int s[512];
    int v = (threadIdx.x < nb) ? bsum[threadIdx.x] : 0;
    s[threadIdx.x] = v;
    __syncthreads();
    for (int off = 1; off < 512; off <<= 1){
        int t = (threadIdx.x >= off) ? s[threadIdx.x - off] : 0;
        __syncthreads();
        s[threadIdx.x] += t;
        __syncthreads();
    }
    if (threadIdx.x < nb) bsum[threadIdx.x] = s[threadIdx.x];
}

__global__ void scan3_kernel(const int* __restrict__ part, const int* __restrict__ din,
                             const int* __restrict__ bsum, int* __restrict__ offs,
                             int* __restrict__ cur, int n){
    int i = blockIdx.x * 256 + threadIdx.x;
    if (i < n){
        int base = (blockIdx.x > 0) ? bsum[blockIdx.x - 1] : 0;
        int excl = base + part[i] - din[i];
        offs[i] = excl;
        cur[i]  = excl;
    }
}

__global__ void fill_kernel(const int* __restrict__ src, const int* __restrict__ dst,
                            int* __restrict__ cur, int* __restrict__ csr){
    int e = blockIdx.x * blockDim.x + threadIdx.x;
    if (e < NE_EDGES){
        int d = dst[e];
        int pos = atomicAdd(&cur[d], 1);
        csr[pos] = src[e];
    }
}

// ---------------- APPNP propagation v3.1: 8 lanes per node, 2-way unrolled ----------------
__global__ __launch_bounds__(256) void propagate_kernel(
    const _Float16* __restrict__ hs, const _Float16* __restrict__ h0h,
    float* __restrict__ hout, _Float16* __restrict__ houts,
    const int* __restrict__ offs, const int* __restrict__ din,
    const int* __restrict__ csr,
    const float* __restrict__ ns, const float* __restrict__ nd)
{
    int t    = blockIdx.x * 256 + threadIdx.x;
    int node = t >> 3;
    int gl   = t & 7;
    if (node >= NN_NODES) return;
    int start = offs[node];
    int deg   = din[node];
    float acc[8] = {};
    int j = 0;
    for (; j + 2 <= deg; j += 2){
        int s0 = csr[start + j];
        int s1 = csr[start + j + 1];
        h16x8 v0 = *(const h16x8*)(hs + (size_t)s0 * D_C + gl * 8);
        h16x8 v1 = *(const h16x8*)(hs + (size_t)s1 * D_C + gl * 8);
        #pragma unroll
        for (int i = 0; i < 8; i++) acc[i] += (float)v0[i] + (float)v1[i];
    }
    if (j < deg){
        int s0 = csr[start + j];
        h16x8 v0 = *(const h16x8*)(hs + (size_t)s0 * D_C + gl * 8);
        #pragma unroll
        for (int i = 0; i < 8; i++) acc[i] += (float)v0[i];
    }
    float ndv = 0.9f * nd[node];
    h16x8 h0v = *(const h16x8*)(h0h + (size_t)node * D_C + gl * 8);
    float out[8];
    #pragma unroll
    for (int i = 0; i < 8; i++) out[i] = acc[i] * ndv + 0.1f * (float)h0v[i];
    if (houts){
        float nsv = ns[node];
        h16x8 o;
        #pragma unroll
        for (int i = 0; i < 8; i++) o[i] = (_Float16)(out[i] * nsv);
        *(h16x8*)(houts + (size_t)node * D_C + gl * 8) = o;
    }
    if (hout){
        f32x4 oa, ob;
        #pragma unroll
        for (int i = 0; i < 4; i++){ oa[i] = out[i]; ob[i] = out[i + 4]; }
        *(f32x4*)(hout + (size_t)node * D_C + gl * 8)     = oa;
        *(f32x4*)(hout + (size_t)node * D_C + gl * 8 + 4) = ob;
    }
}

// ---------------- launch ----------------
extern "C" void kernel_launch(void* const* d_in, const int* in_sizes, int n_in,
                              void* d_out, int out_size, void* d_ws, size_t ws_size,
                              hipStream_t stream)
{
    const float* features = (const float*)d_in[0];
    const int*   edge     = (const int*)d_in[1];
    const float* W0 = (const float*)d_in[2];
    const float* b0 = (const float*)d_in[3];
    const float* W1 = (const float*)d_in[4];
    const float* b1 = (const float*)d_in[5];
    const float* W2 = (const float*)d_in[6];
    const float* b2 = (const float*)d_in[7];
    const int* src = edge;
    const int* dst = edge + NE_EDGES;

    char* p = (char*)d_ws;
    auto alloc = [&](size_t bytes) -> char* {
        char* r = p;
        p += (bytes + 255) & ~(size_t)255;
        return r;
    };

    const int MT = (NN_NODES + 127) / 128;              // 782 m-tiles
    const size_t FEAT_T = (size_t)MT * 16 * 4096 * 2;   // tiled fp16, K=512
    const size_t HBUFH  = (size_t)NN_NODES * D_C * 2;   // 12.8 MB fp16

    _Float16* w0f = (_Float16*)alloc((size_t)4 * 16 * 4096 * 2);  // 512 rows
    _Float16* w1f = (_Float16*)alloc((size_t)2 * 16 * 4096 * 2);  // 256 rows
    _Float16* w2f = (_Float16*)alloc((size_t)1 * 8  * 4096 * 2);  // 64 rows
    char* R1 = alloc(FEAT_T);          // fhf (tiled); later act2 (tiled)
    char* R2 = alloc(FEAT_T);          // act1 (tiled); later h0h + h0s + hAs + hBs
    int*   deg_out = (int*)alloc((size_t)NN_NODES * 4);
    int*   deg_in  = (int*)alloc((size_t)NN_NODES * 4);
    float* nsrc    = (float*)alloc((size_t)NN_NODES * 4);
    float* ndst    = (float*)alloc((size_t)NN_NODES * 4);
    int*   part    = (int*)alloc((size_t)NN_NODES * 4);
    int*   bsum    = (int*)alloc(2048);
    int*   offs    = (int*)alloc((size_t)NN_NODES * 4);
    int*   cur     = (int*)alloc((size_t)NN_NODES * 4);
    int*   csr     = (int*)alloc((size_t)NE_EDGES * 4);
    if ((size_t)(p - (char*)d_ws) > ws_size) return;

    _Float16* fhf  = (_Float16*)R1;          // dead after GEMM1
    _Float16* act2 = (_Float16*)R1;          // written by GEMM2 (tiled)
    _Float16* act1 = (_Float16*)R2;          // dead after GEMM2
    _Float16* h0h  = (_Float16*)R2;          // written by GEMM3 (row-major fp16)
    _Float16* h0s  = (_Float16*)(R2 + HBUFH);
    _Float16* hAs  = (_Float16*)(R2 + 2 * HBUFH);
    _Float16* hBs  = (_Float16*)(R2 + 3 * HBUFH);

    // --- graph preprocessing ---
    hipMemsetAsync(deg_out, 0, (size_t)NN_NODES * 4, stream);
    hipMemsetAsync(deg_in,  0, (size_t)NN_NODES * 4, stream);
    degrees_kernel<<<(NE_EDGES + 255) / 256, 256, 0, stream>>>(src, dst, deg_out, deg_in);
    norm_kernel<<<(NN_NODES + 255) / 256, 256, 0, stream>>>(deg_out, deg_in, nsrc, ndst, NN_NODES);
    int nb = (NN_NODES + 255) / 256;
    scan1_kernel<<<nb, 256, 0, stream>>>(deg_in, part, bsum, NN_NODES);
    scan2_kernel<<<1, 512, 0, stream>>>(bsum, nb);
    scan3_kernel<<<nb, 256, 0, stream>>>(part, deg_in, bsum, offs, cur, NN_NODES);
    fill_kernel<<<(NE_EDGES + 255) / 256, 256, 0, stream>>>(src, dst, cur, csr);

    // --- conversions (fp32 row-major -> fp16 tiled) ---
    tof16_tiled_kernel<<<(NN_NODES * D_IN / 8 + 255) / 256, 256, 0, stream>>>(
        features, fhf, NN_NODES, D_IN);
    tof16_tiled_kernel<<<(D_H0 * D_IN / 8 + 255) / 256, 256, 0, stream>>>(W0, w0f, D_H0, D_IN);
    tof16_tiled_kernel<<<(D_H1 * D_H0 / 8 + 255) / 256, 256, 0, stream>>>(W1, w1f, D_H1, D_H0);
    tof16_tiled_kernel<<<(D_C * D_H1 / 8 + 255) / 256, 256, 0, stream>>>(W2, w2f, D_C, D_H1);

    // --- MLP (BN_T=64 everywhere: acc fits under the 128-reg bucket) ---
    {   // L0: [100k,512] x [512,512]^T, relu, tiled fp16 out
        int nwg = MT * 8;
        gemm_kernel<true, 1, 64, 8, 512><<<nwg, 256, 0, stream>>>(
            fhf, w0f, b0, act1, nullptr, nullptr, NN_NODES, D_H0, nwg / 8, nwg % 8);
    }
    {   // L1: [100k,512] x [256,512]^T, relu, tiled fp16 out
        int nwg = MT * 4;
        gemm_kernel<true, 1, 64, 4, 512><<<nwg, 256, 0, stream>>>(
            act1, w1f, b1, act2, nullptr, nullptr, NN_NODES, D_H1, nwg / 8, nwg % 8);
    }
    {   // L2: [100k,256] x [64,256]^T, dual row-major fp16 out (h0h, h0s=h0*ns)
        int nwg = MT;
        gemm_kernel<false, 2, 64, 1, 256><<<nwg, 256, 0, stream>>>(
            act2, w2f, b2, h0h, h0s, nsrc, NN_NODES, D_C, nwg / 8, nwg % 8);
    }

    // --- APPNP: 10 propagation steps (8 lanes per node) ---
    const _Float16* curs = h0s;
    _Float16* bufss[2] = { hAs, hBs };
    int pb = (NN_NODES * 8 + 255) / 256;   // 3125 blocks
    for (int it = 0; it < 10; it++){
        float*    out  = (it == 9) ? (float*)d_out : nullptr;
        _Float16* outs = (it == 9) ? nullptr       : bufss[it & 1];
        propagate_kernel<<<pb, 256, 0, stream>>>(curs, h0h, out, outs, offs, deg_in, csr, nsrc, ndst);
        curs = outs;
    }
}